// Round 1
// baseline (797.720 us; speedup 1.0000x reference)
//
#include <hip/hip_runtime.h>
#include <stdint.h>

typedef unsigned short u16;
typedef __attribute__((ext_vector_type(4))) unsigned short u16x4;
typedef __attribute__((ext_vector_type(8))) unsigned short u16x8;
typedef __attribute__((ext_vector_type(8))) short bf16x8;
typedef __attribute__((ext_vector_type(4))) float f32x4;
typedef __attribute__((ext_vector_type(4))) float f4v;

__device__ __forceinline__ float b2f(u16 u) {
    union { unsigned u; float f; } c; c.u = ((unsigned)u) << 16; return c.f;
}
__device__ __forceinline__ u16 f2b(float f) {
    union { float f; unsigned u; } c; c.f = f;
    unsigned r = c.u + 0x7fffu + ((c.u >> 16) & 1u);
    return (u16)(r >> 16);
}

// ---------------- fp32 -> bf16 conversion (vectorized) ----------------
__global__ void f2b_kernel(const float* __restrict__ in, u16* __restrict__ out, int n4) {
    int i = blockIdx.x * blockDim.x + threadIdx.x;
    int stride = gridDim.x * blockDim.x;
    for (; i < n4; i += stride) {
        f4v v = ((const f4v*)in)[i];
        u16x4 o;
        o[0] = f2b(v[0]); o[1] = f2b(v[1]); o[2] = f2b(v[2]); o[3] = f2b(v[3]);
        ((u16x4*)out)[i] = o;
    }
}

// ---------------- CSR build ----------------
__global__ void count_kernel(const int* __restrict__ ei, int* __restrict__ deg, int E) {
    int e = blockIdx.x * blockDim.x + threadIdx.x;
    if (e < E) atomicAdd(&deg[ei[E + e]], 1);
}

__global__ void scan_kernel(const int* __restrict__ deg, int* __restrict__ rowp, int n) {
    __shared__ int sm[1024];
    __shared__ int running;
    int tid = threadIdx.x;
    if (tid == 0) running = 0;
    __syncthreads();
    for (int base = 0; base < n; base += 1024) {
        int i = base + tid;
        int v = (i < n) ? deg[i] : 0;
        sm[tid] = v;
        __syncthreads();
        for (int off = 1; off < 1024; off <<= 1) {
            int t = (tid >= off) ? sm[tid - off] : 0;
            __syncthreads();
            sm[tid] += t;
            __syncthreads();
        }
        int incl = sm[tid];
        int r = running;
        if (i < n) rowp[i] = r + incl - v;
        __syncthreads();
        if (tid == 1023) running = r + incl;
        __syncthreads();
    }
    if (tid == 0) rowp[n] = running;
}

__global__ void fill_kernel(const int* __restrict__ ei, const int* __restrict__ rowp,
                            int* __restrict__ cnt, int* __restrict__ col, int E) {
    int e = blockIdx.x * blockDim.x + threadIdx.x;
    if (e < E) {
        int dst = ei[E + e];
        int pos = atomicAdd(&cnt[dst], 1);
        col[rowp[dst] + pos] = ei[e];
    }
}

// ---------------- GIN aggregation: t[i] = sum_{j in N(i)} h[j] + (2+eps)*h[i] ----------------
// one wave per node, 8 bf16 per lane (512 features)
__global__ void agg_kernel(const u16* __restrict__ h, u16* __restrict__ t,
                           const int* __restrict__ rowp, const int* __restrict__ col,
                           const float* __restrict__ epsp, int N) {
    int w = (blockIdx.x * blockDim.x + threadIdx.x) >> 6;
    if (w >= N) return;
    int lane = threadIdx.x & 63;
    float coef = 2.0f + epsp[0];
    size_t off = (size_t)lane * 8;
    u16x8 s = *(const u16x8*)(h + (size_t)w * 512 + off);
    float acc[8];
#pragma unroll
    for (int j = 0; j < 8; j++) acc[j] = coef * b2f(s[j]);
    int p = rowp[w], e = rowp[w + 1];
    for (; p + 2 <= e; p += 2) {
        int s0 = col[p], s1 = col[p + 1];
        u16x8 v0 = *(const u16x8*)(h + (size_t)s0 * 512 + off);
        u16x8 v1 = *(const u16x8*)(h + (size_t)s1 * 512 + off);
#pragma unroll
        for (int j = 0; j < 8; j++) acc[j] += b2f(v0[j]) + b2f(v1[j]);
    }
    if (p < e) {
        int s0 = col[p];
        u16x8 v0 = *(const u16x8*)(h + (size_t)s0 * 512 + off);
#pragma unroll
        for (int j = 0; j < 8; j++) acc[j] += b2f(v0[j]);
    }
    u16x8 o;
#pragma unroll
    for (int j = 0; j < 8; j++) o[j] = f2b(acc[j]);
    *(u16x8*)(t + (size_t)w * 512 + off) = o;
}

// ---------------- MFMA GEMM: C[M][Nout] = leakyrelu(A[M][K] @ W[Nout][K]^T + bias) ----------------
// 128x128 tile, BK=32, 4 waves of 64x64; A,W bf16 row-major K-contiguous (NT layout)
#define BM 128
#define BN 128
#define BK 32
#define LDR 40  // LDS row stride in u16 (32 + 8 pad => 80B, 16B aligned, <=2-way bank alias)

template <typename OutT>
__launch_bounds__(256)
__global__ void gemm_bt_kernel(const u16* __restrict__ A, const u16* __restrict__ W,
                               const float* __restrict__ bias, OutT* __restrict__ C,
                               int M, int Nout, int K) {
    __shared__ alignas(16) u16 lA[BM * LDR];
    __shared__ alignas(16) u16 lB[BN * LDR];
    int tid = threadIdx.x;
    int lane = tid & 63;
    int wv = tid >> 6;
    int m0 = blockIdx.x * BM;
    int n0 = blockIdx.y * BN;
    int wrow = (wv >> 1) * 64;
    int wcol = (wv & 1) * 64;

    f32x4 acc[4][4];
#pragma unroll
    for (int i = 0; i < 4; i++)
#pragma unroll
        for (int j = 0; j < 4; j++) acc[i][j] = (f32x4){0.f, 0.f, 0.f, 0.f};

    // staging coords: each thread loads 16B; rows tid/4 and tid/4+64, col (tid%4)*8
    int srow = tid >> 2;
    int scol = (tid & 3) * 8;
    int ar0 = m0 + srow;       if (ar0 >= M) ar0 = M - 1;
    int ar1 = m0 + srow + 64;  if (ar1 >= M) ar1 = M - 1;
    const u16* Ap0 = A + (size_t)ar0 * K + scol;
    const u16* Ap1 = A + (size_t)ar1 * K + scol;
    const u16* Wp0 = W + (size_t)(n0 + srow) * K + scol;
    const u16* Wp1 = W + (size_t)(n0 + srow + 64) * K + scol;
    u16* sa0 = lA + srow * LDR + scol;
    u16* sa1 = lA + (srow + 64) * LDR + scol;
    u16* sb0 = lB + srow * LDR + scol;
    u16* sb1 = lB + (srow + 64) * LDR + scol;

    int fr = lane & 15;
    int kq = (lane >> 4) * 8;

    for (int kt = 0; kt < K; kt += BK) {
        u16x8 a0 = *(const u16x8*)(Ap0 + kt);
        u16x8 a1 = *(const u16x8*)(Ap1 + kt);
        u16x8 b0 = *(const u16x8*)(Wp0 + kt);
        u16x8 b1 = *(const u16x8*)(Wp1 + kt);
        __syncthreads();  // previous iteration's reads complete
        *(u16x8*)sa0 = a0;
        *(u16x8*)sa1 = a1;
        *(u16x8*)sb0 = b0;
        *(u16x8*)sb1 = b1;
        __syncthreads();

        bf16x8 af[4], bfr[4];
#pragma unroll
        for (int m = 0; m < 4; m++)
            af[m] = *(const bf16x8*)(lA + (wrow + m * 16 + fr) * LDR + kq);
#pragma unroll
        for (int nf = 0; nf < 4; nf++)
            bfr[nf] = *(const bf16x8*)(lB + (wcol + nf * 16 + fr) * LDR + kq);
#pragma unroll
        for (int m = 0; m < 4; m++)
#pragma unroll
            for (int nf = 0; nf < 4; nf++)
                acc[m][nf] = __builtin_amdgcn_mfma_f32_16x16x32_bf16(af[m], bfr[nf], acc[m][nf], 0, 0, 0);
    }

    // epilogue: C/D layout col=lane&15, row=(lane>>4)*4+reg  [m89-verified]
    int r0 = (lane >> 4) * 4;
#pragma unroll
    for (int m = 0; m < 4; m++) {
#pragma unroll
        for (int nf = 0; nf < 4; nf++) {
            int gc = n0 + wcol + nf * 16 + fr;
            float bv = bias[gc];
#pragma unroll
            for (int r = 0; r < 4; r++) {
                int gr = m0 + wrow + m * 16 + r0 + r;
                if (gr < M) {
                    float v = acc[m][nf][r] + bv;
                    v = (v >= 0.f) ? v : 0.2f * v;
                    if constexpr (sizeof(OutT) == 2)
                        ((u16*)C)[(size_t)gr * Nout + gc] = f2b(v);
                    else
                        ((float*)C)[(size_t)gr * Nout + gc] = v;
                }
            }
        }
    }
}

// ---------------- final fc: out[k][f] = x3[cidx[k]] . Wfc[f] + bfc[f] (fp32) ----------------
__global__ void fc_kernel(const float* __restrict__ x3, const int* __restrict__ cidx,
                          const float* __restrict__ W, const float* __restrict__ b,
                          float* __restrict__ out, int C, int F) {
    __shared__ float xr[256];
    int k = blockIdx.x;
    int node = cidx[k];
    int tid = threadIdx.x;
    xr[tid] = x3[(size_t)node * C + tid];
    __syncthreads();
    for (int f = tid; f < F; f += 256) {
        const float4* wr = (const float4*)(W + (size_t)f * C);
        float acc = 0.f;
#pragma unroll 8
        for (int c4 = 0; c4 < C / 4; ++c4) {
            float4 wv = wr[c4];
            acc += xr[c4 * 4 + 0] * wv.x + xr[c4 * 4 + 1] * wv.y +
                   xr[c4 * 4 + 2] * wv.z + xr[c4 * 4 + 3] * wv.w;
        }
        out[(size_t)k * F + f] = acc + b[f];
    }
}

extern "C" void kernel_launch(void* const* d_in, const int* in_sizes, int n_in,
                              void* d_out, int out_size, void* d_ws, size_t ws_size,
                              hipStream_t stream) {
    const float* x    = (const float*)d_in[0];
    const int*   ei   = (const int*)d_in[1];
    const int*   cidx = (const int*)d_in[2];
    const float* W1   = (const float*)d_in[3];
    const float* b1   = (const float*)d_in[4];
    const float* eps1 = (const float*)d_in[5];
    const float* W2   = (const float*)d_in[6];
    const float* b2   = (const float*)d_in[7];
    const float* eps2 = (const float*)d_in[8];
    const float* W3   = (const float*)d_in[9];
    const float* b3   = (const float*)d_in[10];
    const float* eps3 = (const float*)d_in[11];
    const float* Wfc  = (const float*)d_in[12];
    const float* bfc  = (const float*)d_in[13];

    const int F = 512, H = 512, Cc = 256;
    const int Nn = in_sizes[0] / F;   // 50000
    const int E  = in_sizes[1] / 2;   // 800000
    const int Kc = in_sizes[2];       // 1024

    // workspace layout (bytes)
    const size_t SZ_BUF = (size_t)Nn * 512 * 2;  // 51.2 MB
    char* ws = (char*)d_ws;
    u16* bufA = (u16*)ws;
    u16* bufB = (u16*)(ws + SZ_BUF);
    u16* W1b  = (u16*)(ws + 2 * SZ_BUF);
    u16* W2b  = W1b + 262144;
    u16* W3b  = W2b + 262144;
    int* deg  = (int*)(ws + 2 * SZ_BUF + 2u * (262144 + 262144 + 131072));
    int* rowp = deg + Nn;
    int* colx = rowp + Nn + 1;

    // 1) convert x, W1..W3 to bf16
    f2b_kernel<<<2048, 256, 0, stream>>>(x, bufA, (Nn * F) / 4);
    f2b_kernel<<<256, 256, 0, stream>>>(W1, W1b, 262144 / 4);
    f2b_kernel<<<256, 256, 0, stream>>>(W2, W2b, 262144 / 4);
    f2b_kernel<<<128, 256, 0, stream>>>(W3, W3b, 131072 / 4);

    // 2) build CSR (dst -> list of src)
    hipMemsetAsync(deg, 0, (size_t)Nn * sizeof(int), stream);
    count_kernel<<<(E + 255) / 256, 256, 0, stream>>>(ei, deg, E);
    scan_kernel<<<1, 1024, 0, stream>>>(deg, rowp, Nn);
    hipMemsetAsync(deg, 0, (size_t)Nn * sizeof(int), stream);
    fill_kernel<<<(E + 255) / 256, 256, 0, stream>>>(ei, rowp, deg, colx, E);

    int aggBlocks = (Nn * 64 + 255) / 256;
    dim3 g512((Nn + BM - 1) / BM, H / BN);
    dim3 g256((Nn + BM - 1) / BM, Cc / BN);

    // 3) layer 1
    agg_kernel<<<aggBlocks, 256, 0, stream>>>(bufA, bufB, rowp, colx, eps1, Nn);
    gemm_bt_kernel<u16><<<g512, 256, 0, stream>>>(bufB, W1b, b1, bufA, Nn, H, F);
    // 4) layer 2
    agg_kernel<<<aggBlocks, 256, 0, stream>>>(bufA, bufB, rowp, colx, eps2, Nn);
    gemm_bt_kernel<u16><<<g512, 256, 0, stream>>>(bufB, W2b, b2, bufA, Nn, H, H);
    // 5) layer 3 -> fp32 x3 directly into d_out
    agg_kernel<<<aggBlocks, 256, 0, stream>>>(bufA, bufB, rowp, colx, eps3, Nn);
    float* x3 = (float*)d_out;
    gemm_bt_kernel<float><<<g256, 256, 0, stream>>>(bufB, W3b, b3, x3, Nn, Cc, H);

    // 6) fc on gathered central rows (fp32)
    float* outp = x3 + (size_t)Nn * Cc;
    fc_kernel<<<Kc, 256, 0, stream>>>(x3, cidx, Wfc, bfc, outp, Cc, F);
}

// Round 2
// 714.213 us; speedup vs baseline: 1.1169x; 1.1169x over previous
//
#include <hip/hip_runtime.h>
#include <stdint.h>

typedef unsigned short u16;
typedef __attribute__((ext_vector_type(4))) unsigned short u16x4;
typedef __attribute__((ext_vector_type(8))) unsigned short u16x8;
typedef __attribute__((ext_vector_type(8))) short bf16x8;
typedef __attribute__((ext_vector_type(4))) float f32x4;
typedef __attribute__((ext_vector_type(4))) float f4v;

__device__ __forceinline__ float b2f(u16 u) {
    union { unsigned u; float f; } c; c.u = ((unsigned)u) << 16; return c.f;
}
__device__ __forceinline__ u16 f2b(float f) {
    union { float f; unsigned u; } c; c.f = f;
    unsigned r = c.u + 0x7fffu + ((c.u >> 16) & 1u);
    return (u16)(r >> 16);
}

// async global->LDS 16B (per-lane global src, wave-uniform LDS base + lane*16)
__device__ __forceinline__ void gload16(const u16* g, u16* l) {
    __builtin_amdgcn_global_load_lds(
        (const __attribute__((address_space(1))) unsigned int*)g,
        (__attribute__((address_space(3))) unsigned int*)l, 16, 0, 0);
}

// ---------------- fp32 -> bf16 conversion (vectorized) ----------------
__global__ void f2b_kernel(const float* __restrict__ in, u16* __restrict__ out, int n4) {
    int i = blockIdx.x * blockDim.x + threadIdx.x;
    int stride = gridDim.x * blockDim.x;
    for (; i < n4; i += stride) {
        f4v v = ((const f4v*)in)[i];
        u16x4 o;
        o[0] = f2b(v[0]); o[1] = f2b(v[1]); o[2] = f2b(v[2]); o[3] = f2b(v[3]);
        ((u16x4*)out)[i] = o;
    }
}

// ---------------- CSR build ----------------
__global__ void count_kernel(const int* __restrict__ ei, int* __restrict__ deg, int E) {
    int e = blockIdx.x * blockDim.x + threadIdx.x;
    if (e < E) atomicAdd(&deg[ei[E + e]], 1);
}

// chunked scan: 1024 threads, each owns ceil(n/1024) contiguous elements
__global__ void scan_kernel(const int* __restrict__ deg, int* __restrict__ rowp, int n) {
    __shared__ int sm[1024];
    int tid = threadIdx.x;
    int per = (n + 1023) / 1024;
    int start = tid * per;
    int end = start + per; if (end > n) end = n;
    int s = 0;
    for (int i = start; i < end; i++) s += deg[i];
    sm[tid] = s;
    __syncthreads();
    for (int off = 1; off < 1024; off <<= 1) {
        int t = (tid >= off) ? sm[tid - off] : 0;
        __syncthreads();
        sm[tid] += t;
        __syncthreads();
    }
    int run = sm[tid] - s;  // exclusive prefix of this chunk
    for (int i = start; i < end; i++) { rowp[i] = run; run += deg[i]; }
    if (tid == 1023) rowp[n] = sm[1023];
}

__global__ void fill_kernel(const int* __restrict__ ei, const int* __restrict__ rowp,
                            int* __restrict__ cnt, int* __restrict__ col, int E) {
    int e = blockIdx.x * blockDim.x + threadIdx.x;
    if (e < E) {
        int dst = ei[E + e];
        int pos = atomicAdd(&cnt[dst], 1);
        col[rowp[dst] + pos] = ei[e];
    }
}

// ---------------- GIN aggregation (512 feats): t[i] = sum_{j in N(i)} h[j] + (2+eps)*h[i] ----
// one wave per node, 8 bf16/lane, unroll-4 edge gathers for ILP
__global__ void agg_kernel(const u16* __restrict__ h, u16* __restrict__ t,
                           const int* __restrict__ rowp, const int* __restrict__ col,
                           const float* __restrict__ epsp, int N) {
    int w = (blockIdx.x * blockDim.x + threadIdx.x) >> 6;
    if (w >= N) return;
    int lane = threadIdx.x & 63;
    float coef = 2.0f + epsp[0];
    size_t off = (size_t)lane * 8;
    u16x8 s = *(const u16x8*)(h + (size_t)w * 512 + off);
    float acc[8];
#pragma unroll
    for (int j = 0; j < 8; j++) acc[j] = coef * b2f(s[j]);
    int p = rowp[w], e = rowp[w + 1];
    for (; p + 4 <= e; p += 4) {
        int s0 = col[p], s1 = col[p + 1], s2 = col[p + 2], s3 = col[p + 3];
        u16x8 v0 = *(const u16x8*)(h + (size_t)s0 * 512 + off);
        u16x8 v1 = *(const u16x8*)(h + (size_t)s1 * 512 + off);
        u16x8 v2 = *(const u16x8*)(h + (size_t)s2 * 512 + off);
        u16x8 v3 = *(const u16x8*)(h + (size_t)s3 * 512 + off);
#pragma unroll
        for (int j = 0; j < 8; j++)
            acc[j] += (b2f(v0[j]) + b2f(v1[j])) + (b2f(v2[j]) + b2f(v3[j]));
    }
    for (; p < e; p++) {
        int s0 = col[p];
        u16x8 v0 = *(const u16x8*)(h + (size_t)s0 * 512 + off);
#pragma unroll
        for (int j = 0; j < 8; j++) acc[j] += b2f(v0[j]);
    }
    u16x8 o;
#pragma unroll
    for (int j = 0; j < 8; j++) o[j] = f2b(acc[j]);
    *(u16x8*)(t + (size_t)w * 512 + off) = o;
}

// ---------------- layer-3 aggregation on 256 feats with fused epilogue -> fp32 ----------------
// x3[i] = leaky( sum_{j in N(i)} g[j] + (2+eps)*g[i] + b3 )
__global__ void agg3_kernel(const u16* __restrict__ g, float* __restrict__ out,
                            const int* __restrict__ rowp, const int* __restrict__ col,
                            const float* __restrict__ epsp, const float* __restrict__ bias,
                            int N) {
    int w = (blockIdx.x * blockDim.x + threadIdx.x) >> 6;
    if (w >= N) return;
    int lane = threadIdx.x & 63;
    float coef = 2.0f + epsp[0];
    size_t off = (size_t)lane * 4;
    f4v bv = *(const f4v*)(bias + off);
    u16x4 s = *(const u16x4*)(g + (size_t)w * 256 + off);
    float acc[4];
#pragma unroll
    for (int j = 0; j < 4; j++) acc[j] = coef * b2f(s[j]);
    int p = rowp[w], e = rowp[w + 1];
    for (; p + 4 <= e; p += 4) {
        int s0 = col[p], s1 = col[p + 1], s2 = col[p + 2], s3 = col[p + 3];
        u16x4 v0 = *(const u16x4*)(g + (size_t)s0 * 256 + off);
        u16x4 v1 = *(const u16x4*)(g + (size_t)s1 * 256 + off);
        u16x4 v2 = *(const u16x4*)(g + (size_t)s2 * 256 + off);
        u16x4 v3 = *(const u16x4*)(g + (size_t)s3 * 256 + off);
#pragma unroll
        for (int j = 0; j < 4; j++)
            acc[j] += (b2f(v0[j]) + b2f(v1[j])) + (b2f(v2[j]) + b2f(v3[j]));
    }
    for (; p < e; p++) {
        int s0 = col[p];
        u16x4 v0 = *(const u16x4*)(g + (size_t)s0 * 256 + off);
#pragma unroll
        for (int j = 0; j < 4; j++) acc[j] += b2f(v0[j]);
    }
    f4v o;
#pragma unroll
    for (int j = 0; j < 4; j++) {
        float v = acc[j] + bv[j];
        o[j] = (v >= 0.f) ? v : 0.2f * v;
    }
    *(f4v*)(out + (size_t)w * 256 + off) = o;
}

// ---------------- MFMA GEMM (m97 structure): C = [act](A[M][K] @ W[Nout][K]^T [+ bias]) ----
// 128x128 tile, BK=32, 4 waves of 64x64, global_load_lds width-16 staging, linear LDS
#define BM 128
#define BN 128
#define BK 32

template <typename OutT, bool ACT>
__launch_bounds__(256)
__global__ void gemm_bt_kernel(const u16* __restrict__ A, const u16* __restrict__ W,
                               const float* __restrict__ bias, OutT* __restrict__ C,
                               int M, int Nout, int K) {
    __shared__ alignas(16) u16 lA[BM * BK];
    __shared__ alignas(16) u16 lB[BN * BK];
    int tid = threadIdx.x;
    int lane = tid & 63;
    int wv = tid >> 6;
    int m0 = blockIdx.x * BM;
    int n0 = blockIdx.y * BN;
    int wrow = (wv >> 1) * 64;
    int wcol = (wv & 1) * 64;

    f32x4 acc[4][4];
#pragma unroll
    for (int i = 0; i < 4; i++)
#pragma unroll
        for (int j = 0; j < 4; j++) acc[i][j] = (f32x4){0.f, 0.f, 0.f, 0.f};

    // staging: per wave, 2 calls each for A and B. Call c covers rows c*64+wv*16 .. +16,
    // lane l -> row +(l>>2), 16B slot (l&3). LDS row = 32 u16 = 64B, linear.
    int srow = lane >> 2;          // 0..15
    int scol = (lane & 3) * 8;     // u16 col within row
    int arow0 = m0 + wv * 16 + srow;        if (arow0 >= M) arow0 = M - 1;
    int arow1 = m0 + 64 + wv * 16 + srow;   if (arow1 >= M) arow1 = M - 1;
    const u16* gA0 = A + (size_t)arow0 * K + scol;
    const u16* gA1 = A + (size_t)arow1 * K + scol;
    const u16* gB0 = W + (size_t)(n0 + wv * 16 + srow) * K + scol;
    const u16* gB1 = W + (size_t)(n0 + 64 + wv * 16 + srow) * K + scol;
    u16* lA0 = lA + (wv * 16) * BK;
    u16* lA1 = lA + (64 + wv * 16) * BK;
    u16* lB0 = lB + (wv * 16) * BK;
    u16* lB1 = lB + (64 + wv * 16) * BK;

    int fr = lane & 15;
    int kq = (lane >> 4) * 8;

    for (int kt = 0; kt < K; kt += BK) {
        __syncthreads();  // prev iteration's ds_reads done before overwrite
        gload16(gA0 + kt, lA0);
        gload16(gA1 + kt, lA1);
        gload16(gB0 + kt, lB0);
        gload16(gB1 + kt, lB1);
        __syncthreads();  // compiler drains vmcnt(0) before barrier

        bf16x8 af[4], bfr[4];
#pragma unroll
        for (int m = 0; m < 4; m++)
            af[m] = *(const bf16x8*)(lA + (wrow + m * 16 + fr) * BK + kq);
#pragma unroll
        for (int nf = 0; nf < 4; nf++)
            bfr[nf] = *(const bf16x8*)(lB + (wcol + nf * 16 + fr) * BK + kq);
#pragma unroll
        for (int m = 0; m < 4; m++)
#pragma unroll
            for (int nf = 0; nf < 4; nf++)
                acc[m][nf] = __builtin_amdgcn_mfma_f32_16x16x32_bf16(af[m], bfr[nf], acc[m][nf], 0, 0, 0);
    }

    // epilogue: C/D layout col=lane&15, row=(lane>>4)*4+reg  [m89-verified]
    int r0 = (lane >> 4) * 4;
#pragma unroll
    for (int m = 0; m < 4; m++) {
#pragma unroll
        for (int nf = 0; nf < 4; nf++) {
            int gc = n0 + wcol + nf * 16 + fr;
            float bv = ACT ? bias[gc] : 0.f;
#pragma unroll
            for (int r = 0; r < 4; r++) {
                int gr = m0 + wrow + m * 16 + r0 + r;
                if (gr < M) {
                    float v = acc[m][nf][r] + bv;
                    if constexpr (ACT) v = (v >= 0.f) ? v : 0.2f * v;
                    if constexpr (sizeof(OutT) == 2)
                        ((u16*)C)[(size_t)gr * Nout + gc] = f2b(v);
                    else
                        ((float*)C)[(size_t)gr * Nout + gc] = v;
                }
            }
        }
    }
}

// ---------------- final fc: out[k][f] = x3[cidx[k]] . Wfc[f] + bfc[f] (fp32) ----------------
__global__ void fc_kernel(const float* __restrict__ x3, const int* __restrict__ cidx,
                          const float* __restrict__ W, const float* __restrict__ b,
                          float* __restrict__ out, int C, int F) {
    __shared__ float xr[256];
    int k = blockIdx.x;
    int node = cidx[k];
    int tid = threadIdx.x;
    xr[tid] = x3[(size_t)node * C + tid];
    __syncthreads();
    for (int f = tid; f < F; f += 256) {
        const float4* wr = (const float4*)(W + (size_t)f * C);
        float acc = 0.f;
#pragma unroll 8
        for (int c4 = 0; c4 < C / 4; ++c4) {
            float4 wv = wr[c4];
            acc += xr[c4 * 4 + 0] * wv.x + xr[c4 * 4 + 1] * wv.y +
                   xr[c4 * 4 + 2] * wv.z + xr[c4 * 4 + 3] * wv.w;
        }
        out[(size_t)k * F + f] = acc + b[f];
    }
}

extern "C" void kernel_launch(void* const* d_in, const int* in_sizes, int n_in,
                              void* d_out, int out_size, void* d_ws, size_t ws_size,
                              hipStream_t stream) {
    const float* x    = (const float*)d_in[0];
    const int*   ei   = (const int*)d_in[1];
    const int*   cidx = (const int*)d_in[2];
    const float* W1   = (const float*)d_in[3];
    const float* b1   = (const float*)d_in[4];
    const float* eps1 = (const float*)d_in[5];
    const float* W2   = (const float*)d_in[6];
    const float* b2   = (const float*)d_in[7];
    const float* eps2 = (const float*)d_in[8];
    const float* W3   = (const float*)d_in[9];
    const float* b3   = (const float*)d_in[10];
    const float* eps3 = (const float*)d_in[11];
    const float* Wfc  = (const float*)d_in[12];
    const float* bfc  = (const float*)d_in[13];

    const int F = 512, H = 512, Cc = 256;
    const int Nn = in_sizes[0] / F;   // 50000
    const int E  = in_sizes[1] / 2;   // 800000
    const int Kc = in_sizes[2];       // 1024

    // workspace layout (bytes)
    const size_t SZ_BUF = (size_t)Nn * 512 * 2;  // 51.2 MB
    char* ws = (char*)d_ws;
    u16* bufA = (u16*)ws;
    u16* bufB = (u16*)(ws + SZ_BUF);
    u16* W1b  = (u16*)(ws + 2 * SZ_BUF);
    u16* W2b  = W1b + 262144;
    u16* W3b  = W2b + 262144;
    int* deg  = (int*)(ws + 2 * SZ_BUF + 2u * (262144 + 262144 + 131072));
    int* rowp = deg + Nn;
    int* colx = rowp + Nn + 1;

    // 1) convert x, W1..W3 to bf16
    f2b_kernel<<<2048, 256, 0, stream>>>(x, bufA, (Nn * F) / 4);
    f2b_kernel<<<256, 256, 0, stream>>>(W1, W1b, 262144 / 4);
    f2b_kernel<<<256, 256, 0, stream>>>(W2, W2b, 262144 / 4);
    f2b_kernel<<<128, 256, 0, stream>>>(W3, W3b, 131072 / 4);

    // 2) build CSR (dst -> list of src)
    hipMemsetAsync(deg, 0, (size_t)Nn * sizeof(int), stream);
    count_kernel<<<(E + 255) / 256, 256, 0, stream>>>(ei, deg, E);
    scan_kernel<<<1, 1024, 0, stream>>>(deg, rowp, Nn);
    hipMemsetAsync(deg, 0, (size_t)Nn * sizeof(int), stream);
    fill_kernel<<<(E + 255) / 256, 256, 0, stream>>>(ei, rowp, deg, colx, E);

    int aggBlocks = (Nn * 64 + 255) / 256;
    dim3 g512((Nn + BM - 1) / BM, H / BN);
    dim3 g256((Nn + BM - 1) / BM, Cc / BN);

    // 3) layer 1
    agg_kernel<<<aggBlocks, 256, 0, stream>>>(bufA, bufB, rowp, colx, eps1, Nn);
    gemm_bt_kernel<u16, true><<<g512, 256, 0, stream>>>(bufB, W1b, b1, bufA, Nn, H, F);
    // 4) layer 2
    agg_kernel<<<aggBlocks, 256, 0, stream>>>(bufA, bufB, rowp, colx, eps2, Nn);
    gemm_bt_kernel<u16, true><<<g512, 256, 0, stream>>>(bufB, W2b, b2, bufA, Nn, H, H);
    // 5) layer 3 commuted: g = h2 @ W3^T (no bias/act), then aggregate on 256 feats
    gemm_bt_kernel<u16, false><<<g256, 256, 0, stream>>>(bufA, W3b, b3, bufB, Nn, Cc, H);
    float* x3 = (float*)d_out;
    agg3_kernel<<<aggBlocks, 256, 0, stream>>>(bufB, x3, rowp, colx, eps3, b3, Nn);

    // 6) fc on gathered central rows (fp32)
    float* outp = x3 + (size_t)Nn * Cc;
    fc_kernel<<<Kc, 256, 0, stream>>>(x3, cidx, Wfc, bfc, outp, Cc, F);
}

// Round 3
// 697.495 us; speedup vs baseline: 1.1437x; 1.0240x over previous
//
#include <hip/hip_runtime.h>
#include <stdint.h>

typedef unsigned short u16;
typedef __attribute__((ext_vector_type(4))) unsigned short u16x4;
typedef __attribute__((ext_vector_type(8))) unsigned short u16x8;
typedef __attribute__((ext_vector_type(8))) short bf16x8;
typedef __attribute__((ext_vector_type(4))) float f32x4;
typedef __attribute__((ext_vector_type(4))) float f4v;

__device__ __forceinline__ float b2f(u16 u) {
    union { unsigned u; float f; } c; c.u = ((unsigned)u) << 16; return c.f;
}
__device__ __forceinline__ u16 f2b(float f) {
    union { float f; unsigned u; } c; c.f = f;
    unsigned r = c.u + 0x7fffu + ((c.u >> 16) & 1u);
    return (u16)(r >> 16);
}

// async global->LDS 16B (per-lane global src, wave-uniform LDS base + lane*16)
__device__ __forceinline__ void gload16(const u16* g, u16* l) {
    __builtin_amdgcn_global_load_lds(
        (const __attribute__((address_space(1))) unsigned int*)g,
        (__attribute__((address_space(3))) unsigned int*)l, 16, 0, 0);
}

__device__ __forceinline__ void cvt4(const float* in, u16* out, int idx) {
    f4v v = ((const f4v*)in)[idx];
    u16x4 o;
    o[0] = f2b(v[0]); o[1] = f2b(v[1]); o[2] = f2b(v[2]); o[3] = f2b(v[3]);
    ((u16x4*)out)[idx] = o;
}

// ---------------- merged preamble: f2b(x,W1,W2,W3) + edge count ----------------
// block ranges: [0,2048) x | [2048,2304) W1 | [2304,2560) W2 | [2560,2688) W3 | [2688,5813) count
__global__ void prep_kernel(const float* __restrict__ x, u16* __restrict__ xb, int n4x,
                            const float* __restrict__ W1, u16* __restrict__ W1b,
                            const float* __restrict__ W2, u16* __restrict__ W2b,
                            const float* __restrict__ W3, u16* __restrict__ W3b,
                            const int* __restrict__ ei, int* __restrict__ deg, int E) {
    int b = blockIdx.x;
    int tid = threadIdx.x;
    if (b < 2048) {
        for (int i = b * 256 + tid; i < n4x; i += 2048 * 256) cvt4(x, xb, i);
    } else if (b < 2304) {
        cvt4(W1, W1b, (b - 2048) * 256 + tid);        // 65536 float4
    } else if (b < 2560) {
        cvt4(W2, W2b, (b - 2304) * 256 + tid);        // 65536 float4
    } else if (b < 2688) {
        cvt4(W3, W3b, (b - 2560) * 256 + tid);        // 32768 float4
    } else {
        int e = (b - 2688) * 256 + tid;
        if (e < E) atomicAdd(&deg[ei[E + e]], 1);
    }
}

// chunked scan: 1024 threads, each owns ceil(n/1024) contiguous elements
__global__ void scan_kernel(const int* __restrict__ deg, int* __restrict__ rowp, int n) {
    __shared__ int sm[1024];
    int tid = threadIdx.x;
    int per = (n + 1023) / 1024;
    int start = tid * per;
    int end = start + per; if (end > n) end = n;
    int s = 0;
    for (int i = start; i < end; i++) s += deg[i];
    sm[tid] = s;
    __syncthreads();
    for (int off = 1; off < 1024; off <<= 1) {
        int t = (tid >= off) ? sm[tid - off] : 0;
        __syncthreads();
        sm[tid] += t;
        __syncthreads();
    }
    int run = sm[tid] - s;  // exclusive prefix of this chunk
    for (int i = start; i < end; i++) { rowp[i] = run; run += deg[i]; }
    if (tid == 1023) rowp[n] = sm[1023];
}

__global__ void fill_kernel(const int* __restrict__ ei, const int* __restrict__ rowp,
                            int* __restrict__ cnt, int* __restrict__ col, int E) {
    int e = blockIdx.x * blockDim.x + threadIdx.x;
    if (e < E) {
        int dst = ei[E + e];
        int pos = atomicAdd(&cnt[dst], 1);
        col[rowp[dst] + pos] = ei[e];
    }
}

// ---------------- GIN aggregation (512 feats): t[i] = sum_{j in N(i)} h[j] + (2+eps)*h[i] ----
// one wave per node, 8 bf16/lane, 2-deep gather (R0 form: unroll-4 measured worse)
__global__ void agg_kernel(const u16* __restrict__ h, u16* __restrict__ t,
                           const int* __restrict__ rowp, const int* __restrict__ col,
                           const float* __restrict__ epsp, int N) {
    int w = (blockIdx.x * blockDim.x + threadIdx.x) >> 6;
    if (w >= N) return;
    int lane = threadIdx.x & 63;
    float coef = 2.0f + epsp[0];
    size_t off = (size_t)lane * 8;
    u16x8 s = *(const u16x8*)(h + (size_t)w * 512 + off);
    float acc[8];
#pragma unroll
    for (int j = 0; j < 8; j++) acc[j] = coef * b2f(s[j]);
    int p = rowp[w], e = rowp[w + 1];
    for (; p + 2 <= e; p += 2) {
        int s0 = col[p], s1 = col[p + 1];
        u16x8 v0 = *(const u16x8*)(h + (size_t)s0 * 512 + off);
        u16x8 v1 = *(const u16x8*)(h + (size_t)s1 * 512 + off);
#pragma unroll
        for (int j = 0; j < 8; j++) acc[j] += b2f(v0[j]) + b2f(v1[j]);
    }
    if (p < e) {
        int s0 = col[p];
        u16x8 v0 = *(const u16x8*)(h + (size_t)s0 * 512 + off);
#pragma unroll
        for (int j = 0; j < 8; j++) acc[j] += b2f(v0[j]);
    }
    u16x8 o;
#pragma unroll
    for (int j = 0; j < 8; j++) o[j] = f2b(acc[j]);
    *(u16x8*)(t + (size_t)w * 512 + off) = o;
}

// ---------------- layer-3 aggregation on 256 feats with fused epilogue -> fp32 ----------------
__global__ void agg3_kernel(const u16* __restrict__ g, float* __restrict__ out,
                            const int* __restrict__ rowp, const int* __restrict__ col,
                            const float* __restrict__ epsp, const float* __restrict__ bias,
                            int N) {
    int w = (blockIdx.x * blockDim.x + threadIdx.x) >> 6;
    if (w >= N) return;
    int lane = threadIdx.x & 63;
    float coef = 2.0f + epsp[0];
    size_t off = (size_t)lane * 4;
    f4v bv = *(const f4v*)(bias + off);
    u16x4 s = *(const u16x4*)(g + (size_t)w * 256 + off);
    float acc[4];
#pragma unroll
    for (int j = 0; j < 4; j++) acc[j] = coef * b2f(s[j]);
    int p = rowp[w], e = rowp[w + 1];
    for (; p + 2 <= e; p += 2) {
        int s0 = col[p], s1 = col[p + 1];
        u16x4 v0 = *(const u16x4*)(g + (size_t)s0 * 256 + off);
        u16x4 v1 = *(const u16x4*)(g + (size_t)s1 * 256 + off);
#pragma unroll
        for (int j = 0; j < 4; j++) acc[j] += b2f(v0[j]) + b2f(v1[j]);
    }
    if (p < e) {
        int s0 = col[p];
        u16x4 v0 = *(const u16x4*)(g + (size_t)s0 * 256 + off);
#pragma unroll
        for (int j = 0; j < 4; j++) acc[j] += b2f(v0[j]);
    }
    f4v o;
#pragma unroll
    for (int j = 0; j < 4; j++) {
        float v = acc[j] + bv[j];
        o[j] = (v >= 0.f) ? v : 0.2f * v;
    }
    *(f4v*)(out + (size_t)w * 256 + off) = o;
}

// ---------------- MFMA GEMM, 2-phase double-buffered (T3-minimum recipe) ----------------
// C = [act](A[M][K] @ W[Nout][K]^T [+ bias]); 128x128 tile, BK=32, 4 waves of 64x64.
// STAGE(t+1) issued BEFORE compute(t); one __syncthreads per K-step (drains vmcnt+lgkm).
#define BM 128
#define BN 128
#define BK 32

template <typename OutT, bool ACT>
__launch_bounds__(256)
__global__ void gemm_bt_kernel(const u16* __restrict__ A, const u16* __restrict__ W,
                               const float* __restrict__ bias, OutT* __restrict__ C,
                               int M, int Nout, int K) {
    __shared__ alignas(16) u16 lA[2][BM * BK];
    __shared__ alignas(16) u16 lB[2][BN * BK];
    int tid = threadIdx.x;
    int lane = tid & 63;
    int wv = tid >> 6;
    int m0 = blockIdx.x * BM;
    int n0 = blockIdx.y * BN;
    int wrow = (wv >> 1) * 64;
    int wcol = (wv & 1) * 64;

    f32x4 acc[4][4];
#pragma unroll
    for (int i = 0; i < 4; i++)
#pragma unroll
        for (int j = 0; j < 4; j++) acc[i][j] = (f32x4){0.f, 0.f, 0.f, 0.f};

    // staging: per wave 2 gloads each for A and B (16 rows x 32 cols = 1KB per gload)
    int srow = lane >> 2;          // 0..15
    int scol = (lane & 3) * 8;     // u16 col within row
    int arow0 = m0 + wv * 16 + srow;        if (arow0 >= M) arow0 = M - 1;
    int arow1 = m0 + 64 + wv * 16 + srow;   if (arow1 >= M) arow1 = M - 1;
    const u16* gA0 = A + (size_t)arow0 * K + scol;
    const u16* gA1 = A + (size_t)arow1 * K + scol;
    const u16* gB0 = W + (size_t)(n0 + wv * 16 + srow) * K + scol;
    const u16* gB1 = W + (size_t)(n0 + 64 + wv * 16 + srow) * K + scol;
    int la0 = (wv * 16) * BK;
    int la1 = (64 + wv * 16) * BK;

    int fr = lane & 15;
    int kq = (lane >> 4) * 8;
    int nt = K / BK;

    // prologue: stage tile 0
    gload16(gA0, lA[0] + la0);
    gload16(gA1, lA[0] + la1);
    gload16(gB0, lB[0] + la0);
    gload16(gB1, lB[0] + la1);
    __syncthreads();

    for (int t = 0; t < nt; t++) {
        int cur = t & 1;
        if (t + 1 < nt) {  // issue next-tile stage BEFORE compute — latency hides under MFMA
            int kt = (t + 1) * BK;
            gload16(gA0 + kt, lA[cur ^ 1] + la0);
            gload16(gA1 + kt, lA[cur ^ 1] + la1);
            gload16(gB0 + kt, lB[cur ^ 1] + la0);
            gload16(gB1 + kt, lB[cur ^ 1] + la1);
        }
        bf16x8 af[4], bfr[4];
#pragma unroll
        for (int m = 0; m < 4; m++)
            af[m] = *(const bf16x8*)(lA[cur] + (wrow + m * 16 + fr) * BK + kq);
#pragma unroll
        for (int nf = 0; nf < 4; nf++)
            bfr[nf] = *(const bf16x8*)(lB[cur] + (wcol + nf * 16 + fr) * BK + kq);
#pragma unroll
        for (int m = 0; m < 4; m++)
#pragma unroll
            for (int nf = 0; nf < 4; nf++)
                acc[m][nf] = __builtin_amdgcn_mfma_f32_16x16x32_bf16(af[m], bfr[nf], acc[m][nf], 0, 0, 0);
        __syncthreads();  // drains vmcnt(0)+lgkmcnt: next buffer ready, cur free for overwrite
    }

    // epilogue: C/D layout col=lane&15, row=(lane>>4)*4+reg  [m89-verified]
    int r0 = (lane >> 4) * 4;
#pragma unroll
    for (int m = 0; m < 4; m++) {
#pragma unroll
        for (int nf = 0; nf < 4; nf++) {
            int gc = n0 + wcol + nf * 16 + fr;
            float bv = ACT ? bias[gc] : 0.f;
#pragma unroll
            for (int r = 0; r < 4; r++) {
                int gr = m0 + wrow + m * 16 + r0 + r;
                if (gr < M) {
                    float v = acc[m][nf][r] + bv;
                    if constexpr (ACT) v = (v >= 0.f) ? v : 0.2f * v;
                    if constexpr (sizeof(OutT) == 2)
                        ((u16*)C)[(size_t)gr * Nout + gc] = f2b(v);
                    else
                        ((float*)C)[(size_t)gr * Nout + gc] = v;
                }
            }
        }
    }
}

// ---------------- final fc: out[k][f] = x3[cidx[k]] . Wfc[f] + bfc[f] (fp32) ----------------
__global__ void fc_kernel(const float* __restrict__ x3, const int* __restrict__ cidx,
                          const float* __restrict__ W, const float* __restrict__ b,
                          float* __restrict__ out, int C, int F) {
    __shared__ float xr[256];
    int k = blockIdx.x;
    int node = cidx[k];
    int tid = threadIdx.x;
    xr[tid] = x3[(size_t)node * C + tid];
    __syncthreads();
    for (int f = tid; f < F; f += 256) {
        const float4* wr = (const float4*)(W + (size_t)f * C);
        float acc = 0.f;
#pragma unroll 8
        for (int c4 = 0; c4 < C / 4; ++c4) {
            float4 wv = wr[c4];
            acc += xr[c4 * 4 + 0] * wv.x + xr[c4 * 4 + 1] * wv.y +
                   xr[c4 * 4 + 2] * wv.z + xr[c4 * 4 + 3] * wv.w;
        }
        out[(size_t)k * F + f] = acc + b[f];
    }
}

extern "C" void kernel_launch(void* const* d_in, const int* in_sizes, int n_in,
                              void* d_out, int out_size, void* d_ws, size_t ws_size,
                              hipStream_t stream) {
    const float* x    = (const float*)d_in[0];
    const int*   ei   = (const int*)d_in[1];
    const int*   cidx = (const int*)d_in[2];
    const float* W1   = (const float*)d_in[3];
    const float* b1   = (const float*)d_in[4];
    const float* eps1 = (const float*)d_in[5];
    const float* W2   = (const float*)d_in[6];
    const float* b2   = (const float*)d_in[7];
    const float* eps2 = (const float*)d_in[8];
    const float* W3   = (const float*)d_in[9];
    const float* b3   = (const float*)d_in[10];
    const float* eps3 = (const float*)d_in[11];
    const float* Wfc  = (const float*)d_in[12];
    const float* bfc  = (const float*)d_in[13];

    const int F = 512, H = 512, Cc = 256;
    const int Nn = in_sizes[0] / F;   // 50000
    const int E  = in_sizes[1] / 2;   // 800000
    const int Kc = in_sizes[2];       // 1024

    // workspace layout (bytes)
    const size_t SZ_BUF = (size_t)Nn * 512 * 2;  // 51.2 MB
    char* ws = (char*)d_ws;
    u16* bufA = (u16*)ws;
    u16* bufB = (u16*)(ws + SZ_BUF);
    u16* W1b  = (u16*)(ws + 2 * SZ_BUF);
    u16* W2b  = W1b + 262144;
    u16* W3b  = W2b + 262144;
    int* deg  = (int*)(ws + 2 * SZ_BUF + 2u * (262144 + 262144 + 131072));
    int* cnt  = deg + Nn;
    int* rowp = cnt + Nn;
    int* colx = rowp + Nn + 1;

    // 1) zero deg+cnt (adjacent) in one memset, then merged preamble
    hipMemsetAsync(deg, 0, 2 * (size_t)Nn * sizeof(int), stream);
    int prepBlocks = 2688 + (E + 255) / 256;
    prep_kernel<<<prepBlocks, 256, 0, stream>>>(x, bufA, (Nn * F) / 4,
                                                W1, W1b, W2, W2b, W3, W3b,
                                                ei, deg, E);
    scan_kernel<<<1, 1024, 0, stream>>>(deg, rowp, Nn);
    fill_kernel<<<(E + 255) / 256, 256, 0, stream>>>(ei, rowp, cnt, colx, E);

    int aggBlocks = (Nn * 64 + 255) / 256;
    dim3 g512((Nn + BM - 1) / BM, H / BN);
    dim3 g256((Nn + BM - 1) / BM, Cc / BN);

    // 2) layer 1
    agg_kernel<<<aggBlocks, 256, 0, stream>>>(bufA, bufB, rowp, colx, eps1, Nn);
    gemm_bt_kernel<u16, true><<<g512, 256, 0, stream>>>(bufB, W1b, b1, bufA, Nn, H, F);
    // 3) layer 2
    agg_kernel<<<aggBlocks, 256, 0, stream>>>(bufA, bufB, rowp, colx, eps2, Nn);
    gemm_bt_kernel<u16, true><<<g512, 256, 0, stream>>>(bufB, W2b, b2, bufA, Nn, H, H);
    // 4) layer 3 commuted: g = h2 @ W3^T (no bias/act), then aggregate on 256 feats
    gemm_bt_kernel<u16, false><<<g256, 256, 0, stream>>>(bufA, W3b, b3, bufB, Nn, Cc, H);
    float* x3 = (float*)d_out;
    agg3_kernel<<<aggBlocks, 256, 0, stream>>>(bufB, x3, rowp, colx, eps3, b3, Nn);

    // 5) fc on gathered central rows (fp32)
    float* outp = x3 + (size_t)Nn * Cc;
    fc_kernel<<<Kc, 256, 0, stream>>>(x3, cidx, Wfc, bfc, outp, Cc, F);
}

// Round 4
// 616.334 us; speedup vs baseline: 1.2943x; 1.1317x over previous
//
#include <hip/hip_runtime.h>
#include <stdint.h>

typedef unsigned short u16;
typedef __attribute__((ext_vector_type(4))) unsigned short u16x4;
typedef __attribute__((ext_vector_type(8))) unsigned short u16x8;
typedef __attribute__((ext_vector_type(8))) short bf16x8;
typedef __attribute__((ext_vector_type(4))) float f32x4;
typedef __attribute__((ext_vector_type(4))) float f4v;

__device__ __forceinline__ float b2f(u16 u) {
    union { unsigned u; float f; } c; c.u = ((unsigned)u) << 16; return c.f;
}
__device__ __forceinline__ u16 f2b(float f) {
    union { float f; unsigned u; } c; c.f = f;
    unsigned r = c.u + 0x7fffu + ((c.u >> 16) & 1u);
    return (u16)(r >> 16);
}

// async global->LDS 16B
__device__ __forceinline__ void gload16(const u16* g, u16* l) {
    __builtin_amdgcn_global_load_lds(
        (const __attribute__((address_space(1))) unsigned int*)g,
        (__attribute__((address_space(3))) unsigned int*)l, 16, 0, 0);
}

__device__ __forceinline__ void cvt4(const float* in, u16* out, int idx) {
    f4v v = ((const f4v*)in)[idx];
    u16x4 o;
    o[0] = f2b(v[0]); o[1] = f2b(v[1]); o[2] = f2b(v[2]); o[3] = f2b(v[3]);
    ((u16x4*)out)[idx] = o;
}

// dequant 8 int8 (packed int2) with scale s, accumulate
__device__ __forceinline__ void dq_acc(int2 d, float s, float* acc) {
#pragma unroll
    for (int j = 0; j < 4; j++) acc[j]     += s * (float)(signed char)(d.x >> (8 * j));
#pragma unroll
    for (int j = 0; j < 4; j++) acc[j + 4] += s * (float)(signed char)(d.y >> (8 * j));
}
__device__ __forceinline__ void dq_acc4(int d, float s, float* acc) {
#pragma unroll
    for (int j = 0; j < 4; j++) acc[j] += s * (float)(signed char)(d >> (8 * j));
}

__device__ __forceinline__ float wave_max(float m) {
#pragma unroll
    for (int d = 1; d < 64; d <<= 1) m = fmaxf(m, __shfl_xor(m, d));
    return m;
}

// ---------------- merged preamble ----------------
// [0,12500): quantize x fp32 -> int8 per-row (wave per node, 4 nodes/block)
// [12500,12756) W1 | [12756,13012) W2 | [13012,13140) W3 | [13140,16265) edge count
__global__ void prep_kernel(const float* __restrict__ x, char* __restrict__ qx,
                            float* __restrict__ xs,
                            const float* __restrict__ W1, u16* __restrict__ W1b,
                            const float* __restrict__ W2, u16* __restrict__ W2b,
                            const float* __restrict__ W3, u16* __restrict__ W3b,
                            const int* __restrict__ ei, int* __restrict__ deg, int E) {
    int b = blockIdx.x;
    int tid = threadIdx.x;
    if (b < 12500) {
        int w = b * 4 + (tid >> 6);
        int lane = tid & 63;
        const f4v* xr = (const f4v*)(x + (size_t)w * 512) + lane * 2;
        f4v v0 = xr[0], v1 = xr[1];
        float m = 0.f;
#pragma unroll
        for (int j = 0; j < 4; j++) { m = fmaxf(m, fabsf(v0[j])); m = fmaxf(m, fabsf(v1[j])); }
        m = wave_max(m);
        float scale = (m > 0.f) ? 127.f / m : 0.f;
        int lo = 0, hi = 0;
#pragma unroll
        for (int j = 0; j < 4; j++) { int q = (int)rintf(v0[j] * scale); lo |= (q & 0xFF) << (8 * j); }
#pragma unroll
        for (int j = 0; j < 4; j++) { int q = (int)rintf(v1[j] * scale); hi |= (q & 0xFF) << (8 * j); }
        ((int2*)(qx + (size_t)w * 512))[lane] = make_int2(lo, hi);
        if (lane == 0) xs[w] = (m > 0.f) ? m / 127.f : 0.f;
    } else if (b < 12756) {
        cvt4(W1, W1b, (b - 12500) * 256 + tid);
    } else if (b < 13012) {
        cvt4(W2, W2b, (b - 12756) * 256 + tid);
    } else if (b < 13140) {
        cvt4(W3, W3b, (b - 13012) * 256 + tid);
    } else {
        int e = (b - 13140) * 256 + tid;
        if (e < E) atomicAdd(&deg[ei[E + e]], 1);
    }
}

// ---------------- quantize bf16 h (512 feats) -> int8 + per-row scale ----------------
__global__ void quant512_kernel(const u16* __restrict__ h, char* __restrict__ qh,
                                float* __restrict__ hs) {
    int w = blockIdx.x * 4 + (threadIdx.x >> 6);
    int lane = threadIdx.x & 63;
    u16x8 v = ((const u16x8*)(h + (size_t)w * 512))[lane];
    float f[8]; float m = 0.f;
#pragma unroll
    for (int j = 0; j < 8; j++) { f[j] = b2f(v[j]); m = fmaxf(m, fabsf(f[j])); }
    m = wave_max(m);
    float scale = (m > 0.f) ? 127.f / m : 0.f;
    int lo = 0, hi = 0;
#pragma unroll
    for (int j = 0; j < 4; j++) { int q = (int)rintf(f[j] * scale); lo |= (q & 0xFF) << (8 * j); }
#pragma unroll
    for (int j = 0; j < 4; j++) { int q = (int)rintf(f[j + 4] * scale); hi |= (q & 0xFF) << (8 * j); }
    ((int2*)(qh + (size_t)w * 512))[lane] = make_int2(lo, hi);
    if (lane == 0) hs[w] = (m > 0.f) ? m / 127.f : 0.f;
}

// ---------------- quantize bf16 g (256 feats) -> int8 + per-row scale ----------------
__global__ void quant256_kernel(const u16* __restrict__ g, char* __restrict__ qg,
                                float* __restrict__ gs) {
    int w = blockIdx.x * 4 + (threadIdx.x >> 6);
    int lane = threadIdx.x & 63;
    u16x4 v = ((const u16x4*)(g + (size_t)w * 256))[lane];
    float f[4]; float m = 0.f;
#pragma unroll
    for (int j = 0; j < 4; j++) { f[j] = b2f(v[j]); m = fmaxf(m, fabsf(f[j])); }
    m = wave_max(m);
    float scale = (m > 0.f) ? 127.f / m : 0.f;
    int lo = 0;
#pragma unroll
    for (int j = 0; j < 4; j++) { int q = (int)rintf(f[j] * scale); lo |= (q & 0xFF) << (8 * j); }
    ((int*)(qg + (size_t)w * 256))[lane] = lo;
    if (lane == 0) gs[w] = (m > 0.f) ? m / 127.f : 0.f;
}

// chunked scan
__global__ void scan_kernel(const int* __restrict__ deg, int* __restrict__ rowp, int n) {
    __shared__ int sm[1024];
    int tid = threadIdx.x;
    int per = (n + 1023) / 1024;
    int start = tid * per;
    int end = start + per; if (end > n) end = n;
    int s = 0;
    for (int i = start; i < end; i++) s += deg[i];
    sm[tid] = s;
    __syncthreads();
    for (int off = 1; off < 1024; off <<= 1) {
        int t = (tid >= off) ? sm[tid - off] : 0;
        __syncthreads();
        sm[tid] += t;
        __syncthreads();
    }
    int run = sm[tid] - s;
    for (int i = start; i < end; i++) { rowp[i] = run; run += deg[i]; }
    if (tid == 1023) rowp[n] = sm[1023];
}

__global__ void fill_kernel(const int* __restrict__ ei, const int* __restrict__ rowp,
                            int* __restrict__ cnt, int* __restrict__ col, int E) {
    int e = blockIdx.x * blockDim.x + threadIdx.x;
    if (e < E) {
        int dst = ei[E + e];
        int pos = atomicAdd(&cnt[dst], 1);
        col[rowp[dst] + pos] = ei[e];
    }
}

// ---------------- int8 GIN aggregation (512 feats) -> bf16 t ----------------
__global__ void agg_q512(const char* __restrict__ q, const float* __restrict__ sc,
                         u16* __restrict__ t, const int* __restrict__ rowp,
                         const int* __restrict__ col, const float* __restrict__ epsp, int N) {
    int w = (blockIdx.x * blockDim.x + threadIdx.x) >> 6;
    if (w >= N) return;
    int lane = threadIdx.x & 63;
    float coef = 2.0f + epsp[0];
    const int2* base = (const int2*)q;  // 64 int2 per row
    float acc[8];
#pragma unroll
    for (int j = 0; j < 8; j++) acc[j] = 0.f;
    dq_acc(base[(size_t)w * 64 + lane], coef * sc[w], acc);
    int p = rowp[w], e = rowp[w + 1];
    for (; p + 2 <= e; p += 2) {
        int s0 = col[p], s1 = col[p + 1];
        int2 v0 = base[(size_t)s0 * 64 + lane];
        int2 v1 = base[(size_t)s1 * 64 + lane];
        float f0 = sc[s0], f1 = sc[s1];
        dq_acc(v0, f0, acc);
        dq_acc(v1, f1, acc);
    }
    if (p < e) {
        int s0 = col[p];
        dq_acc(base[(size_t)s0 * 64 + lane], sc[s0], acc);
    }
    u16x8 o;
#pragma unroll
    for (int j = 0; j < 8; j++) o[j] = f2b(acc[j]);
    *(u16x8*)(t + (size_t)w * 512 + lane * 8) = o;
}

// ---------------- int8 layer-3 aggregation (256 feats), fused bias+leaky -> fp32 ----------------
__global__ void agg3_q(const char* __restrict__ q, const float* __restrict__ sc,
                       float* __restrict__ out, const int* __restrict__ rowp,
                       const int* __restrict__ col, const float* __restrict__ epsp,
                       const float* __restrict__ bias, int N) {
    int w = (blockIdx.x * blockDim.x + threadIdx.x) >> 6;
    if (w >= N) return;
    int lane = threadIdx.x & 63;
    float coef = 2.0f + epsp[0];
    const int* base = (const int*)q;  // 64 ints per row
    f4v bv = *(const f4v*)(bias + lane * 4);
    float acc[4];
#pragma unroll
    for (int j = 0; j < 4; j++) acc[j] = 0.f;
    dq_acc4(base[(size_t)w * 64 + lane], coef * sc[w], acc);
    int p = rowp[w], e = rowp[w + 1];
    for (; p + 2 <= e; p += 2) {
        int s0 = col[p], s1 = col[p + 1];
        int v0 = base[(size_t)s0 * 64 + lane];
        int v1 = base[(size_t)s1 * 64 + lane];
        float f0 = sc[s0], f1 = sc[s1];
        dq_acc4(v0, f0, acc);
        dq_acc4(v1, f1, acc);
    }
    if (p < e) {
        int s0 = col[p];
        dq_acc4(base[(size_t)s0 * 64 + lane], sc[s0], acc);
    }
    f4v o;
#pragma unroll
    for (int j = 0; j < 4; j++) {
        float v = acc[j] + bv[j];
        o[j] = (v >= 0.f) ? v : 0.2f * v;
    }
    *(f4v*)(out + (size_t)w * 256 + lane * 4) = o;
}

// ---------------- MFMA GEMM, 2-phase dbuf + XCD-chunk swizzle (col-inner) ----------------
#define BM 128
#define BN 128
#define BK 32

template <typename OutT, bool ACT>
__launch_bounds__(256)
__global__ void gemm_bt_kernel(const u16* __restrict__ A, const u16* __restrict__ W,
                               const float* __restrict__ bias, OutT* __restrict__ C,
                               int M, int Nout, int K, int nby) {
    // bijective XCD swizzle (m204): orig round-robins XCDs; give each XCD a
    // contiguous chunk of col-inner work ids so same-A-row blocks share one L2.
    int nwg = gridDim.x;
    int orig = blockIdx.x;
    int q8 = nwg >> 3, r8 = nwg & 7;
    int xcd = orig & 7, idx = orig >> 3;
    int wgid = (xcd < r8 ? xcd * (q8 + 1) : r8 * (q8 + 1) + (xcd - r8) * q8) + idx;
    int by = wgid % nby;
    int bx = wgid / nby;

    __shared__ alignas(16) u16 lA[2][BM * BK];
    __shared__ alignas(16) u16 lB[2][BN * BK];
    int tid = threadIdx.x;
    int lane = tid & 63;
    int wv = tid >> 6;
    int m0 = bx * BM;
    int n0 = by * BN;
    int wrow = (wv >> 1) * 64;
    int wcol = (wv & 1) * 64;

    f32x4 acc[4][4];
#pragma unroll
    for (int i = 0; i < 4; i++)
#pragma unroll
        for (int j = 0; j < 4; j++) acc[i][j] = (f32x4){0.f, 0.f, 0.f, 0.f};

    int srow = lane >> 2;
    int scol = (lane & 3) * 8;
    int arow0 = m0 + wv * 16 + srow;        if (arow0 >= M) arow0 = M - 1;
    int arow1 = m0 + 64 + wv * 16 + srow;   if (arow1 >= M) arow1 = M - 1;
    const u16* gA0 = A + (size_t)arow0 * K + scol;
    const u16* gA1 = A + (size_t)arow1 * K + scol;
    const u16* gB0 = W + (size_t)(n0 + wv * 16 + srow) * K + scol;
    const u16* gB1 = W + (size_t)(n0 + 64 + wv * 16 + srow) * K + scol;
    int la0 = (wv * 16) * BK;
    int la1 = (64 + wv * 16) * BK;

    int fr = lane & 15;
    int kq = (lane >> 4) * 8;
    int nt = K / BK;

    gload16(gA0, lA[0] + la0);
    gload16(gA1, lA[0] + la1);
    gload16(gB0, lB[0] + la0);
    gload16(gB1, lB[0] + la1);
    __syncthreads();

    for (int t = 0; t < nt; t++) {
        int cur = t & 1;
        if (t + 1 < nt) {
            int kt = (t + 1) * BK;
            gload16(gA0 + kt, lA[cur ^ 1] + la0);
            gload16(gA1 + kt, lA[cur ^ 1] + la1);
            gload16(gB0 + kt, lB[cur ^ 1] + la0);
            gload16(gB1 + kt, lB[cur ^ 1] + la1);
        }
        bf16x8 af[4], bfr[4];
#pragma unroll
        for (int m = 0; m < 4; m++)
            af[m] = *(const bf16x8*)(lA[cur] + (wrow + m * 16 + fr) * BK + kq);
#pragma unroll
        for (int nf = 0; nf < 4; nf++)
            bfr[nf] = *(const bf16x8*)(lB[cur] + (wcol + nf * 16 + fr) * BK + kq);
#pragma unroll
        for (int m = 0; m < 4; m++)
#pragma unroll
            for (int nf = 0; nf < 4; nf++)
                acc[m][nf] = __builtin_amdgcn_mfma_f32_16x16x32_bf16(af[m], bfr[nf], acc[m][nf], 0, 0, 0);
        __syncthreads();
    }

    int r0 = (lane >> 4) * 4;
#pragma unroll
    for (int m = 0; m < 4; m++) {
#pragma unroll
        for (int nf = 0; nf < 4; nf++) {
            int gc = n0 + wcol + nf * 16 + fr;
            float bv = ACT ? bias[gc] : 0.f;
#pragma unroll
            for (int r = 0; r < 4; r++) {
                int gr = m0 + wrow + m * 16 + r0 + r;
                if (gr < M) {
                    float v = acc[m][nf][r] + bv;
                    if constexpr (ACT) v = (v >= 0.f) ? v : 0.2f * v;
                    if constexpr (sizeof(OutT) == 2)
                        ((u16*)C)[(size_t)gr * Nout + gc] = f2b(v);
                    else
                        ((float*)C)[(size_t)gr * Nout + gc] = v;
                }
            }
        }
    }
}

// ---------------- final fc ----------------
__global__ void fc_kernel(const float* __restrict__ x3, const int* __restrict__ cidx,
                          const float* __restrict__ W, const float* __restrict__ b,
                          float* __restrict__ out, int C, int F) {
    __shared__ float xr[256];
    int k = blockIdx.x;
    int node = cidx[k];
    int tid = threadIdx.x;
    xr[tid] = x3[(size_t)node * C + tid];
    __syncthreads();
    for (int f = tid; f < F; f += 256) {
        const float4* wr = (const float4*)(W + (size_t)f * C);
        float acc = 0.f;
#pragma unroll 8
        for (int c4 = 0; c4 < C / 4; ++c4) {
            float4 wv = wr[c4];
            acc += xr[c4 * 4 + 0] * wv.x + xr[c4 * 4 + 1] * wv.y +
                   xr[c4 * 4 + 2] * wv.z + xr[c4 * 4 + 3] * wv.w;
        }
        out[(size_t)k * F + f] = acc + b[f];
    }
}

extern "C" void kernel_launch(void* const* d_in, const int* in_sizes, int n_in,
                              void* d_out, int out_size, void* d_ws, size_t ws_size,
                              hipStream_t stream) {
    const float* x    = (const float*)d_in[0];
    const int*   ei   = (const int*)d_in[1];
    const int*   cidx = (const int*)d_in[2];
    const float* W1   = (const float*)d_in[3];
    const float* b1   = (const float*)d_in[4];
    const float* eps1 = (const float*)d_in[5];
    const float* W2   = (const float*)d_in[6];
    const float* b2   = (const float*)d_in[7];
    const float* eps2 = (const float*)d_in[8];
    const float* W3   = (const float*)d_in[9];
    const float* b3   = (const float*)d_in[10];
    const float* eps3 = (const float*)d_in[11];
    const float* Wfc  = (const float*)d_in[12];
    const float* bfc  = (const float*)d_in[13];

    const int F = 512, H = 512, Cc = 256;
    const int Nn = in_sizes[0] / F;   // 50000
    const int E  = in_sizes[1] / 2;   // 800000
    const int Kc = in_sizes[2];       // 1024

    // workspace layout
    const size_t SZ_T = (size_t)Nn * 512 * 2;   // 51.2 MB bf16 t buffer
    const size_t SZ_Q = (size_t)Nn * 512;       // 25.6 MB int8
    char* ws = (char*)d_ws;
    u16*   bufT = (u16*)ws;
    char*  qbuf = ws + SZ_T;
    float* sc   = (float*)(ws + SZ_T + SZ_Q);
    u16*   W1b  = (u16*)(ws + SZ_T + SZ_Q + (size_t)Nn * 4);
    u16*   W2b  = W1b + 262144;
    u16*   W3b  = W2b + 262144;
    int*   deg  = (int*)((char*)(W3b + 131072));
    int*   cnt  = deg + Nn;
    int*   rowp = cnt + Nn;
    int*   colx = rowp + Nn + 1;

    // h1/h2 live in d_out's x3 region (exactly 50000*256 floats = 51.2MB),
    // fully overwritten by agg3_q at the end.
    u16* hbuf = (u16*)d_out;

    hipMemsetAsync(deg, 0, 2 * (size_t)Nn * sizeof(int), stream);
    int prepBlocks = 13140 + (E + 255) / 256;
    prep_kernel<<<prepBlocks, 256, 0, stream>>>(x, qbuf, sc, W1, W1b, W2, W2b, W3, W3b,
                                                ei, deg, E);
    scan_kernel<<<1, 1024, 0, stream>>>(deg, rowp, Nn);
    fill_kernel<<<(E + 255) / 256, 256, 0, stream>>>(ei, rowp, cnt, colx, E);

    int aggBlocks = (Nn * 64 + 255) / 256;
    int nbx = (Nn + BM - 1) / BM;  // 391

    // layer 1
    agg_q512<<<aggBlocks, 256, 0, stream>>>(qbuf, sc, bufT, rowp, colx, eps1, Nn);
    gemm_bt_kernel<u16, true><<<nbx * 4, 256, 0, stream>>>(bufT, W1b, b1, hbuf, Nn, H, F, 4);
    quant512_kernel<<<Nn / 4, 256, 0, stream>>>(hbuf, qbuf, sc);
    // layer 2
    agg_q512<<<aggBlocks, 256, 0, stream>>>(qbuf, sc, bufT, rowp, colx, eps2, Nn);
    gemm_bt_kernel<u16, true><<<nbx * 4, 256, 0, stream>>>(bufT, W2b, b2, hbuf, Nn, H, H, 4);
    // layer 3 commuted: g = h2 @ W3^T (into bufT region), quantize, aggregate
    gemm_bt_kernel<u16, false><<<nbx * 2, 256, 0, stream>>>(hbuf, W3b, b3, bufT, Nn, Cc, H, 2);
    quant256_kernel<<<Nn / 4, 256, 0, stream>>>(bufT, qbuf, sc);
    float* x3 = (float*)d_out;
    agg3_q<<<aggBlocks, 256, 0, stream>>>(qbuf, sc, x3, rowp, colx, eps3, b3, Nn);

    // fc
    float* outp = x3 + (size_t)Nn * Cc;
    fc_kernel<<<Kc, 256, 0, stream>>>(x3, cidx, Wfc, bfc, outp, Cc, F);
}

// Round 5
// 567.109 us; speedup vs baseline: 1.4066x; 1.0868x over previous
//
#include <hip/hip_runtime.h>
#include <stdint.h>

typedef unsigned short u16;
typedef __attribute__((ext_vector_type(4))) unsigned short u16x4;
typedef __attribute__((ext_vector_type(8))) unsigned short u16x8;
typedef __attribute__((ext_vector_type(8))) short bf16x8;
typedef __attribute__((ext_vector_type(4))) float f32x4;
typedef __attribute__((ext_vector_type(4))) float f4v;

__device__ __forceinline__ float b2f(u16 u) {
    union { unsigned u; float f; } c; c.u = ((unsigned)u) << 16; return c.f;
}
__device__ __forceinline__ u16 f2b(float f) {
    union { float f; unsigned u; } c; c.f = f;
    unsigned r = c.u + 0x7fffu + ((c.u >> 16) & 1u);
    return (u16)(r >> 16);
}

// async global->LDS 16B
__device__ __forceinline__ void gload16(const u16* g, u16* l) {
    __builtin_amdgcn_global_load_lds(
        (const __attribute__((address_space(1))) unsigned int*)g,
        (__attribute__((address_space(3))) unsigned int*)l, 16, 0, 0);
}

__device__ __forceinline__ void cvt4(const float* in, u16* out, int idx) {
    f4v v = ((const f4v*)in)[idx];
    u16x4 o;
    o[0] = f2b(v[0]); o[1] = f2b(v[1]); o[2] = f2b(v[2]); o[3] = f2b(v[3]);
    ((u16x4*)out)[idx] = o;
}

// dequant 8 int8 (packed int2) with scale s, accumulate
__device__ __forceinline__ void dq_acc(int2 d, float s, float* acc) {
#pragma unroll
    for (int j = 0; j < 4; j++) acc[j]     += s * (float)(signed char)(d.x >> (8 * j));
#pragma unroll
    for (int j = 0; j < 4; j++) acc[j + 4] += s * (float)(signed char)(d.y >> (8 * j));
}
__device__ __forceinline__ void dq_acc4(int d, float s, float* acc) {
#pragma unroll
    for (int j = 0; j < 4; j++) acc[j] += s * (float)(signed char)(d >> (8 * j));
}

// ---------------- merged preamble ----------------
// [0,12500): quantize x fp32 -> int8 with per-64-feat-chunk scale (wave/node, 4 nodes/block)
// [12500,12756) W1 | [12756,13012) W2 | [13012,13140) W3 | [13140,16265) edge count
__global__ void prep_kernel(const float* __restrict__ x, char* __restrict__ qx,
                            float* __restrict__ xs,
                            const float* __restrict__ W1, u16* __restrict__ W1b,
                            const float* __restrict__ W2, u16* __restrict__ W2b,
                            const float* __restrict__ W3, u16* __restrict__ W3b,
                            const int* __restrict__ ei, int* __restrict__ deg, int E) {
    int b = blockIdx.x;
    int tid = threadIdx.x;
    if (b < 12500) {
        int w = b * 4 + (tid >> 6);
        int lane = tid & 63;
        const f4v* xr = (const f4v*)(x + (size_t)w * 512) + lane * 2;
        f4v v0 = xr[0], v1 = xr[1];
        float m = 0.f;
#pragma unroll
        for (int j = 0; j < 4; j++) { m = fmaxf(m, fabsf(v0[j])); m = fmaxf(m, fabsf(v1[j])); }
        // per-64-feat chunk max: reduce within 8-lane group
#pragma unroll
        for (int d = 1; d < 8; d <<= 1) m = fmaxf(m, __shfl_xor(m, d));
        float scale = (m > 0.f) ? 127.f / m : 0.f;
        int lo = 0, hi = 0;
#pragma unroll
        for (int j = 0; j < 4; j++) { int q = (int)rintf(v0[j] * scale); lo |= (q & 0xFF) << (8 * j); }
#pragma unroll
        for (int j = 0; j < 4; j++) { int q = (int)rintf(v1[j] * scale); hi |= (q & 0xFF) << (8 * j); }
        ((int2*)(qx + (size_t)w * 512))[lane] = make_int2(lo, hi);
        if ((lane & 7) == 0) xs[w * 8 + (lane >> 3)] = (m > 0.f) ? m / 127.f : 0.f;
    } else if (b < 12756) {
        cvt4(W1, W1b, (b - 12500) * 256 + tid);
    } else if (b < 13012) {
        cvt4(W2, W2b, (b - 12756) * 256 + tid);
    } else if (b < 13140) {
        cvt4(W3, W3b, (b - 13012) * 256 + tid);
    } else {
        int e = (b - 13140) * 256 + tid;
        if (e < E) atomicAdd(&deg[ei[E + e]], 1);
    }
}

// chunked scan
__global__ void scan_kernel(const int* __restrict__ deg, int* __restrict__ rowp, int n) {
    __shared__ int sm[1024];
    int tid = threadIdx.x;
    int per = (n + 1023) / 1024;
    int start = tid * per;
    int end = start + per; if (end > n) end = n;
    int s = 0;
    for (int i = start; i < end; i++) s += deg[i];
    sm[tid] = s;
    __syncthreads();
    for (int off = 1; off < 1024; off <<= 1) {
        int t = (tid >= off) ? sm[tid - off] : 0;
        __syncthreads();
        sm[tid] += t;
        __syncthreads();
    }
    int run = sm[tid] - s;
    for (int i = start; i < end; i++) { rowp[i] = run; run += deg[i]; }
    if (tid == 1023) rowp[n] = sm[1023];
}

__global__ void fill_kernel(const int* __restrict__ ei, const int* __restrict__ rowp,
                            int* __restrict__ cnt, int* __restrict__ col, int E) {
    int e = blockIdx.x * blockDim.x + threadIdx.x;
    if (e < E) {
        int dst = ei[E + e];
        int pos = atomicAdd(&cnt[dst], 1);
        col[rowp[dst] + pos] = ei[e];
    }
}

// ---------------- int8 GIN aggregation (512 feats, 8-chunk scales) -> bf16 t ----------------
__global__ void agg_q512(const char* __restrict__ q, const float* __restrict__ sc,
                         u16* __restrict__ t, const int* __restrict__ rowp,
                         const int* __restrict__ col, const float* __restrict__ epsp, int N) {
    int w = (blockIdx.x * blockDim.x + threadIdx.x) >> 6;
    if (w >= N) return;
    w = __builtin_amdgcn_readfirstlane(w);  // SGPR base -> saddr-form loads
    int lane = threadIdx.x & 63;
    float coef = 2.0f + epsp[0];
    const int2* base = (const int2*)q;  // 64 int2 per row
    int ch = lane >> 3;                 // 64-feat chunk of this lane
    float acc[8];
#pragma unroll
    for (int j = 0; j < 8; j++) acc[j] = 0.f;
    dq_acc(base[(size_t)w * 64 + lane], coef * sc[w * 8 + ch], acc);
    int p = rowp[w], e = rowp[w + 1];
    for (; p + 2 <= e; p += 2) {
        int s0 = __builtin_amdgcn_readfirstlane(col[p]);
        int s1 = __builtin_amdgcn_readfirstlane(col[p + 1]);
        int2 v0 = base[(size_t)s0 * 64 + lane];
        int2 v1 = base[(size_t)s1 * 64 + lane];
        float f0 = sc[s0 * 8 + ch];
        float f1 = sc[s1 * 8 + ch];
        dq_acc(v0, f0, acc);
        dq_acc(v1, f1, acc);
    }
    if (p < e) {
        int s0 = __builtin_amdgcn_readfirstlane(col[p]);
        dq_acc(base[(size_t)s0 * 64 + lane], sc[s0 * 8 + ch], acc);
    }
    u16x8 o;
#pragma unroll
    for (int j = 0; j < 8; j++) o[j] = f2b(acc[j]);
    *(u16x8*)(t + (size_t)w * 512 + lane * 8) = o;
}

// ---------------- int8 layer-3 aggregation (256 feats, 4-chunk scales) -> fp32 ----------------
__global__ void agg3_q(const char* __restrict__ q, const float* __restrict__ sc,
                       float* __restrict__ out, const int* __restrict__ rowp,
                       const int* __restrict__ col, const float* __restrict__ epsp,
                       const float* __restrict__ bias, int N) {
    int w = (blockIdx.x * blockDim.x + threadIdx.x) >> 6;
    if (w >= N) return;
    w = __builtin_amdgcn_readfirstlane(w);
    int lane = threadIdx.x & 63;
    float coef = 2.0f + epsp[0];
    const int* base = (const int*)q;  // 64 ints per row
    int ch = lane >> 4;               // 64-feat chunk
    f4v bv = *(const f4v*)(bias + lane * 4);
    float acc[4];
#pragma unroll
    for (int j = 0; j < 4; j++) acc[j] = 0.f;
    dq_acc4(base[(size_t)w * 64 + lane], coef * sc[w * 4 + ch], acc);
    int p = rowp[w], e = rowp[w + 1];
    for (; p + 2 <= e; p += 2) {
        int s0 = __builtin_amdgcn_readfirstlane(col[p]);
        int s1 = __builtin_amdgcn_readfirstlane(col[p + 1]);
        int v0 = base[(size_t)s0 * 64 + lane];
        int v1 = base[(size_t)s1 * 64 + lane];
        float f0 = sc[s0 * 4 + ch];
        float f1 = sc[s1 * 4 + ch];
        dq_acc4(v0, f0, acc);
        dq_acc4(v1, f1, acc);
    }
    if (p < e) {
        int s0 = __builtin_amdgcn_readfirstlane(col[p]);
        dq_acc4(base[(size_t)s0 * 64 + lane], sc[s0 * 4 + ch], acc);
    }
    f4v o;
#pragma unroll
    for (int j = 0; j < 4; j++) {
        float v = acc[j] + bv[j];
        o[j] = (v >= 0.f) ? v : 0.2f * v;
    }
    *(f4v*)(out + (size_t)w * 256 + lane * 4) = o;
}

// ---------------- MFMA GEMM, 2-phase dbuf + XCD-chunk swizzle ----------------
// MODE: 0 = bf16 out, 2 = int8 + per-(row,64col-chunk) scale out (fused quant)
#define BM 128
#define BN 128
#define BK 32

template <int MODE, bool ACT>
__launch_bounds__(256)
__global__ void gemm_bt_kernel(const u16* __restrict__ A, const u16* __restrict__ W,
                               const float* __restrict__ bias, u16* __restrict__ C,
                               char* __restrict__ qc, float* __restrict__ scw,
                               int M, int Nout, int K, int nby) {
    int nwg = gridDim.x;
    int orig = blockIdx.x;
    int q8 = nwg >> 3, r8 = nwg & 7;
    int xcd = orig & 7, idx = orig >> 3;
    int wgid = (xcd < r8 ? xcd * (q8 + 1) : r8 * (q8 + 1) + (xcd - r8) * q8) + idx;
    int by = wgid % nby;
    int bx = wgid / nby;

    __shared__ alignas(16) u16 lA[2][BM * BK];
    __shared__ alignas(16) u16 lB[2][BN * BK];
    int tid = threadIdx.x;
    int lane = tid & 63;
    int wv = tid >> 6;
    int m0 = bx * BM;
    int n0 = by * BN;
    int wrow = (wv >> 1) * 64;
    int wcol = (wv & 1) * 64;

    f32x4 acc[4][4];
#pragma unroll
    for (int i = 0; i < 4; i++)
#pragma unroll
        for (int j = 0; j < 4; j++) acc[i][j] = (f32x4){0.f, 0.f, 0.f, 0.f};

    int srow = lane >> 2;
    int scol = (lane & 3) * 8;
    int arow0 = m0 + wv * 16 + srow;        if (arow0 >= M) arow0 = M - 1;
    int arow1 = m0 + 64 + wv * 16 + srow;   if (arow1 >= M) arow1 = M - 1;
    const u16* gA0 = A + (size_t)arow0 * K + scol;
    const u16* gA1 = A + (size_t)arow1 * K + scol;
    const u16* gB0 = W + (size_t)(n0 + wv * 16 + srow) * K + scol;
    const u16* gB1 = W + (size_t)(n0 + 64 + wv * 16 + srow) * K + scol;
    int la0 = (wv * 16) * BK;
    int la1 = (64 + wv * 16) * BK;

    int fr = lane & 15;
    int kq = (lane >> 4) * 8;
    int nt = K / BK;

    gload16(gA0, lA[0] + la0);
    gload16(gA1, lA[0] + la1);
    gload16(gB0, lB[0] + la0);
    gload16(gB1, lB[0] + la1);
    __syncthreads();

    for (int t = 0; t < nt; t++) {
        int cur = t & 1;
        if (t + 1 < nt) {
            int kt = (t + 1) * BK;
            gload16(gA0 + kt, lA[cur ^ 1] + la0);
            gload16(gA1 + kt, lA[cur ^ 1] + la1);
            gload16(gB0 + kt, lB[cur ^ 1] + la0);
            gload16(gB1 + kt, lB[cur ^ 1] + la1);
        }
        bf16x8 af[4], bfr[4];
#pragma unroll
        for (int m = 0; m < 4; m++)
            af[m] = *(const bf16x8*)(lA[cur] + (wrow + m * 16 + fr) * BK + kq);
#pragma unroll
        for (int nf = 0; nf < 4; nf++)
            bfr[nf] = *(const bf16x8*)(lB[cur] + (wcol + nf * 16 + fr) * BK + kq);
#pragma unroll
        for (int m = 0; m < 4; m++)
#pragma unroll
            for (int nf = 0; nf < 4; nf++)
                acc[m][nf] = __builtin_amdgcn_mfma_f32_16x16x32_bf16(af[m], bfr[nf], acc[m][nf], 0, 0, 0);
        __syncthreads();
    }

    // epilogue: C/D layout col=lane&15, row=(lane>>4)*4+reg
    int r0 = (lane >> 4) * 4;
    if constexpr (MODE == 0) {
#pragma unroll
        for (int m = 0; m < 4; m++) {
#pragma unroll
            for (int nf = 0; nf < 4; nf++) {
                int gc = n0 + wcol + nf * 16 + fr;
                float bv = ACT ? bias[gc] : 0.f;
#pragma unroll
                for (int r = 0; r < 4; r++) {
                    int gr = m0 + wrow + m * 16 + r0 + r;
                    if (gr < M) {
                        float v = acc[m][nf][r] + bv;
                        if constexpr (ACT) v = (v >= 0.f) ? v : 0.2f * v;
                        C[(size_t)gr * Nout + gc] = f2b(v);
                    }
                }
            }
        }
    } else {
        // fused int8 quant: per-(row, 64col) scale via 16-lane shfl reduce
        int nch = Nout >> 6;
        int chunk = (n0 + wcol) >> 6;
#pragma unroll
        for (int m = 0; m < 4; m++) {
            float v[4][4];
#pragma unroll
            for (int nf = 0; nf < 4; nf++) {
                float bv = ACT ? bias[n0 + wcol + nf * 16 + fr] : 0.f;
#pragma unroll
                for (int r = 0; r < 4; r++) {
                    float tv = acc[m][nf][r] + bv;
                    if constexpr (ACT) tv = (tv >= 0.f) ? tv : 0.2f * tv;
                    v[nf][r] = tv;
                }
            }
#pragma unroll
            for (int r = 0; r < 4; r++) {
                float amax = fmaxf(fmaxf(fabsf(v[0][r]), fabsf(v[1][r])),
                                   fmaxf(fabsf(v[2][r]), fabsf(v[3][r])));
#pragma unroll
                for (int d = 1; d < 16; d <<= 1) amax = fmaxf(amax, __shfl_xor(amax, d));
                int gr = m0 + wrow + m * 16 + r0 + r;
                float scale = (amax > 0.f) ? 127.f / amax : 0.f;
                if (gr < M) {
#pragma unroll
                    for (int nf = 0; nf < 4; nf++) {
                        int qv = (int)rintf(v[nf][r] * scale);
                        qc[(size_t)gr * Nout + n0 + wcol + nf * 16 + fr] = (signed char)qv;
                    }
                    if (fr == 0)
                        scw[(size_t)gr * nch + chunk] = (amax > 0.f) ? amax / 127.f : 0.f;
                }
            }
        }
    }
}

// ---------------- final fc ----------------
__global__ void fc_kernel(const float* __restrict__ x3, const int* __restrict__ cidx,
                          const float* __restrict__ W, const float* __restrict__ b,
                          float* __restrict__ out, int C, int F) {
    __shared__ float xr[256];
    int k = blockIdx.x;
    int node = cidx[k];
    int tid = threadIdx.x;
    xr[tid] = x3[(size_t)node * C + tid];
    __syncthreads();
    for (int f = tid; f < F; f += 256) {
        const float4* wr = (const float4*)(W + (size_t)f * C);
        float acc = 0.f;
#pragma unroll 8
        for (int c4 = 0; c4 < C / 4; ++c4) {
            float4 wv = wr[c4];
            acc += xr[c4 * 4 + 0] * wv.x + xr[c4 * 4 + 1] * wv.y +
                   xr[c4 * 4 + 2] * wv.z + xr[c4 * 4 + 3] * wv.w;
        }
        out[(size_t)k * F + f] = acc + b[f];
    }
}

extern "C" void kernel_launch(void* const* d_in, const int* in_sizes, int n_in,
                              void* d_out, int out_size, void* d_ws, size_t ws_size,
                              hipStream_t stream) {
    const float* x    = (const float*)d_in[0];
    const int*   ei   = (const int*)d_in[1];
    const int*   cidx = (const int*)d_in[2];
    const float* W1   = (const float*)d_in[3];
    const float* b1   = (const float*)d_in[4];
    const float* eps1 = (const float*)d_in[5];
    const float* W2   = (const float*)d_in[6];
    const float* b2   = (const float*)d_in[7];
    const float* eps2 = (const float*)d_in[8];
    const float* W3   = (const float*)d_in[9];
    const float* b3   = (const float*)d_in[10];
    const float* eps3 = (const float*)d_in[11];
    const float* Wfc  = (const float*)d_in[12];
    const float* bfc  = (const float*)d_in[13];

    const int F = 512, H = 512, Cc = 256;
    const int Nn = in_sizes[0] / F;   // 50000
    const int E  = in_sizes[1] / 2;   // 800000
    const int Kc = in_sizes[2];       // 1024

    // workspace layout
    const size_t SZ_T = (size_t)Nn * 512 * 2;   // 51.2 MB bf16 t buffer
    const size_t SZ_Q = (size_t)Nn * 512;       // 25.6 MB int8
    char* ws = (char*)d_ws;
    u16*   bufT = (u16*)ws;
    char*  qbuf = ws + SZ_T;
    float* sc   = (float*)(ws + SZ_T + SZ_Q);             // 50k x 8 scales (1.6MB)
    u16*   W1b  = (u16*)(ws + SZ_T + SZ_Q + (size_t)Nn * 32);
    u16*   W2b  = W1b + 262144;
    u16*   W3b  = W2b + 262144;
    int*   deg  = (int*)((char*)(W3b + 131072));
    int*   cnt  = deg + Nn;
    int*   rowp = cnt + Nn;
    int*   colx = rowp + Nn + 1;

    // h2 lives in d_out's x3 region (50000*256 floats = 51.2MB), overwritten by agg3 at the end
    u16* hbuf = (u16*)d_out;

    hipMemsetAsync(deg, 0, 2 * (size_t)Nn * sizeof(int), stream);
    int prepBlocks = 13140 + (E + 255) / 256;
    prep_kernel<<<prepBlocks, 256, 0, stream>>>(x, qbuf, sc, W1, W1b, W2, W2b, W3, W3b,
                                                ei, deg, E);
    scan_kernel<<<1, 1024, 0, stream>>>(deg, rowp, Nn);
    fill_kernel<<<(E + 255) / 256, 256, 0, stream>>>(ei, rowp, cnt, colx, E);

    int aggBlocks = (Nn * 64 + 255) / 256;
    int nbx = (Nn + BM - 1) / BM;  // 391

    // layer 1: agg(qx) -> t1; gemm1 -> int8 h1 (fused quant)
    agg_q512<<<aggBlocks, 256, 0, stream>>>(qbuf, sc, bufT, rowp, colx, eps1, Nn);
    gemm_bt_kernel<2, true><<<nbx * 4, 256, 0, stream>>>(bufT, W1b, b1, nullptr, qbuf, sc,
                                                         Nn, H, F, 4);
    // layer 2: agg(qh1) -> t2; gemm2 -> bf16 h2 (feeds gemm3's MFMA A)
    agg_q512<<<aggBlocks, 256, 0, stream>>>(qbuf, sc, bufT, rowp, colx, eps2, Nn);
    gemm_bt_kernel<0, true><<<nbx * 4, 256, 0, stream>>>(bufT, W2b, b2, hbuf, nullptr, nullptr,
                                                         Nn, H, H, 4);
    // layer 3 commuted: g = h2 @ W3^T -> int8 qg (fused quant); then aggregate
    gemm_bt_kernel<2, false><<<nbx * 2, 256, 0, stream>>>(hbuf, W3b, nullptr, nullptr, qbuf, sc,
                                                          Nn, Cc, H, 2);
    float* x3 = (float*)d_out;
    agg3_q<<<aggBlocks, 256, 0, stream>>>(qbuf, sc, x3, rowp, colx, eps3, b3, Nn);

    // fc
    float* outp = x3 + (size_t)Nn * Cc;
    fc_kernel<<<Kc, 256, 0, stream>>>(x3, cidx, Wfc, bfc, outp, Cc, F);
}

// Round 6
// 520.476 us; speedup vs baseline: 1.5327x; 1.0896x over previous
//
#include <hip/hip_runtime.h>
#include <stdint.h>

typedef unsigned short u16;
typedef __attribute__((ext_vector_type(4))) unsigned short u16x4;
typedef __attribute__((ext_vector_type(8))) unsigned short u16x8;
typedef __attribute__((ext_vector_type(8))) short bf16x8;
typedef __attribute__((ext_vector_type(4))) float f32x4;
typedef __attribute__((ext_vector_type(4))) float f4v;

__device__ __forceinline__ float b2f(u16 u) {
    union { unsigned u; float f; } c; c.u = ((unsigned)u) << 16; return c.f;
}
__device__ __forceinline__ u16 f2b(float f) {
    union { float f; unsigned u; } c; c.f = f;
    unsigned r = c.u + 0x7fffu + ((c.u >> 16) & 1u);
    return (u16)(r >> 16);
}

// async global->LDS 16B
__device__ __forceinline__ void gload16(const u16* g, u16* l) {
    __builtin_amdgcn_global_load_lds(
        (const __attribute__((address_space(1))) unsigned int*)g,
        (__attribute__((address_space(3))) unsigned int*)l, 16, 0, 0);
}

__device__ __forceinline__ void cvt4(const float* in, u16* out, int idx) {
    f4v v = ((const f4v*)in)[idx];
    u16x4 o;
    o[0] = f2b(v[0]); o[1] = f2b(v[1]); o[2] = f2b(v[2]); o[3] = f2b(v[3]);
    ((u16x4*)out)[idx] = o;
}

// dequant 8 int8 (packed int2) with scale s, accumulate
__device__ __forceinline__ void dq_acc(int2 d, float s, float* acc) {
#pragma unroll
    for (int j = 0; j < 4; j++) acc[j]     += s * (float)(signed char)(d.x >> (8 * j));
#pragma unroll
    for (int j = 0; j < 4; j++) acc[j + 4] += s * (float)(signed char)(d.y >> (8 * j));
}
__device__ __forceinline__ void dq_acc4(int d, float s, float* acc) {
#pragma unroll
    for (int j = 0; j < 4; j++) acc[j] += s * (float)(signed char)(d >> (8 * j));
}

// ---------------- merged preamble ----------------
// [0,12500): quantize x fp32 -> int8 with per-64-feat-chunk scale (wave/node, 4 nodes/block)
// [12500,12756) W1 | [12756,13012) W2 | [13012,13140) W3 | [13140,16265) edge count
__global__ void prep_kernel(const float* __restrict__ x, char* __restrict__ qx,
                            float* __restrict__ xs,
                            const float* __restrict__ W1, u16* __restrict__ W1b,
                            const float* __restrict__ W2, u16* __restrict__ W2b,
                            const float* __restrict__ W3, u16* __restrict__ W3b,
                            const int* __restrict__ ei, int* __restrict__ deg, int E) {
    int b = blockIdx.x;
    int tid = threadIdx.x;
    if (b < 12500) {
        int w = b * 4 + (tid >> 6);
        int lane = tid & 63;
        const f4v* xr = (const f4v*)(x + (size_t)w * 512) + lane * 2;
        f4v v0 = xr[0], v1 = xr[1];
        float m = 0.f;
#pragma unroll
        for (int j = 0; j < 4; j++) { m = fmaxf(m, fabsf(v0[j])); m = fmaxf(m, fabsf(v1[j])); }
        // per-64-feat chunk max: reduce within 8-lane group
#pragma unroll
        for (int d = 1; d < 8; d <<= 1) m = fmaxf(m, __shfl_xor(m, d));
        float scale = (m > 0.f) ? 127.f / m : 0.f;
        int lo = 0, hi = 0;
#pragma unroll
        for (int j = 0; j < 4; j++) { int q = (int)rintf(v0[j] * scale); lo |= (q & 0xFF) << (8 * j); }
#pragma unroll
        for (int j = 0; j < 4; j++) { int q = (int)rintf(v1[j] * scale); hi |= (q & 0xFF) << (8 * j); }
        ((int2*)(qx + (size_t)w * 512))[lane] = make_int2(lo, hi);
        if ((lane & 7) == 0) xs[w * 8 + (lane >> 3)] = (m > 0.f) ? m / 127.f : 0.f;
    } else if (b < 12756) {
        cvt4(W1, W1b, (b - 12500) * 256 + tid);
    } else if (b < 13012) {
        cvt4(W2, W2b, (b - 12756) * 256 + tid);
    } else if (b < 13140) {
        cvt4(W3, W3b, (b - 13012) * 256 + tid);
    } else {
        int e = (b - 13140) * 256 + tid;
        if (e < E) atomicAdd(&deg[ei[E + e]], 1);
    }
}

// ---------------- hierarchical scan (3 tiny coalesced phases) ----------------
__global__ void scanA_kernel(const int* __restrict__ deg, int* __restrict__ bsum, int n) {
    __shared__ int sm[256];
    int tid = threadIdx.x;
    int i = blockIdx.x * 256 + tid;
    sm[tid] = (i < n) ? deg[i] : 0;
    __syncthreads();
#pragma unroll
    for (int off = 128; off > 0; off >>= 1) {
        if (tid < off) sm[tid] += sm[tid + off];
        __syncthreads();
    }
    if (tid == 0) bsum[blockIdx.x] = sm[0];
}

__global__ void scanB_kernel(int* __restrict__ bsum, int nb) {
    __shared__ int sm[256];
    int tid = threadIdx.x;
    int v = (tid < nb) ? bsum[tid] : 0;
    sm[tid] = v;
    __syncthreads();
#pragma unroll
    for (int off = 1; off < 256; off <<= 1) {
        int t = (tid >= off) ? sm[tid - off] : 0;
        __syncthreads();
        sm[tid] += t;
        __syncthreads();
    }
    if (tid < nb) bsum[tid] = sm[tid] - v;  // exclusive prefix of block sums
}

__global__ void scanC_kernel(const int* __restrict__ deg, const int* __restrict__ bsum,
                             int* __restrict__ rowp, int n) {
    __shared__ int sm[256];
    int tid = threadIdx.x;
    int b = blockIdx.x;
    int i = b * 256 + tid;
    int v = (i < n) ? deg[i] : 0;
    sm[tid] = v;
    __syncthreads();
#pragma unroll
    for (int off = 1; off < 256; off <<= 1) {
        int t = (tid >= off) ? sm[tid - off] : 0;
        __syncthreads();
        sm[tid] += t;
        __syncthreads();
    }
    if (i < n) rowp[i] = bsum[b] + sm[tid] - v;
    if (i == n - 1) rowp[n] = bsum[b] + sm[tid];
}

__global__ void fill_kernel(const int* __restrict__ ei, const int* __restrict__ rowp,
                            int* __restrict__ cnt, int* __restrict__ col, int E) {
    int e = blockIdx.x * blockDim.x + threadIdx.x;
    if (e < E) {
        int dst = ei[E + e];
        int pos = atomicAdd(&cnt[dst], 1);
        col[rowp[dst] + pos] = ei[e];
    }
}

// ---------------- int8 GIN aggregation (512 feats, 8-chunk scales) -> bf16 t ----------------
__global__ void agg_q512(const char* __restrict__ q, const float* __restrict__ sc,
                         u16* __restrict__ t, const int* __restrict__ rowp,
                         const int* __restrict__ col, const float* __restrict__ epsp, int N) {
    int w = (blockIdx.x * blockDim.x + threadIdx.x) >> 6;
    if (w >= N) return;
    int lane = threadIdx.x & 63;
    float coef = 2.0f + epsp[0];
    const int2* base = (const int2*)q;  // 64 int2 per row
    int ch = lane >> 3;                 // 64-feat chunk of this lane
    float acc[8];
#pragma unroll
    for (int j = 0; j < 8; j++) acc[j] = 0.f;
    dq_acc(base[(size_t)w * 64 + lane], coef * sc[w * 8 + ch], acc);
    int p = rowp[w], e = rowp[w + 1];
    for (; p + 2 <= e; p += 2) {
        int s0 = __builtin_amdgcn_readfirstlane(col[p]);
        int s1 = __builtin_amdgcn_readfirstlane(col[p + 1]);
        int2 v0 = base[(size_t)s0 * 64 + lane];
        int2 v1 = base[(size_t)s1 * 64 + lane];
        float f0 = sc[s0 * 8 + ch];
        float f1 = sc[s1 * 8 + ch];
        dq_acc(v0, f0, acc);
        dq_acc(v1, f1, acc);
    }
    if (p < e) {
        int s0 = __builtin_amdgcn_readfirstlane(col[p]);
        dq_acc(base[(size_t)s0 * 64 + lane], sc[s0 * 8 + ch], acc);
    }
    u16x8 o;
#pragma unroll
    for (int j = 0; j < 8; j++) o[j] = f2b(acc[j]);
    *(u16x8*)(t + (size_t)w * 512 + lane * 8) = o;
}

// ---------------- int8 layer-3 aggregation (256 feats, 4-chunk scales) -> fp32 ----------------
__global__ void agg3_q(const char* __restrict__ q, const float* __restrict__ sc,
                       float* __restrict__ out, const int* __restrict__ rowp,
                       const int* __restrict__ col, const float* __restrict__ epsp,
                       const float* __restrict__ bias, int N) {
    int w = (blockIdx.x * blockDim.x + threadIdx.x) >> 6;
    if (w >= N) return;
    int lane = threadIdx.x & 63;
    float coef = 2.0f + epsp[0];
    const int* base = (const int*)q;  // 64 ints per row
    int ch = lane >> 4;               // 64-feat chunk
    f4v bv = *(const f4v*)(bias + lane * 4);
    float acc[4];
#pragma unroll
    for (int j = 0; j < 4; j++) acc[j] = 0.f;
    dq_acc4(base[(size_t)w * 64 + lane], coef * sc[w * 4 + ch], acc);
    int p = rowp[w], e = rowp[w + 1];
    for (; p + 2 <= e; p += 2) {
        int s0 = __builtin_amdgcn_readfirstlane(col[p]);
        int s1 = __builtin_amdgcn_readfirstlane(col[p + 1]);
        int v0 = base[(size_t)s0 * 64 + lane];
        int v1 = base[(size_t)s1 * 64 + lane];
        float f0 = sc[s0 * 4 + ch];
        float f1 = sc[s1 * 4 + ch];
        dq_acc4(v0, f0, acc);
        dq_acc4(v1, f1, acc);
    }
    if (p < e) {
        int s0 = __builtin_amdgcn_readfirstlane(col[p]);
        dq_acc4(base[(size_t)s0 * 64 + lane], sc[s0 * 4 + ch], acc);
    }
    f4v o;
#pragma unroll
    for (int j = 0; j < 4; j++) {
        float v = acc[j] + bv[j];
        o[j] = (v >= 0.f) ? v : 0.2f * v;
    }
    *(f4v*)(out + (size_t)w * 256 + lane * 4) = o;
}

// ---------------- MFMA GEMM, 2-phase dbuf + XCD-chunk swizzle ----------------
// MODE: 0 = bf16 out, 2 = int8 + per-(row,64col-chunk) scale out (fused quant)
#define BM 128
#define BN 128
#define BK 32

template <int MODE, bool ACT>
__launch_bounds__(256)
__global__ void gemm_bt_kernel(const u16* __restrict__ A, const u16* __restrict__ W,
                               const float* __restrict__ bias, u16* __restrict__ C,
                               char* __restrict__ qc, float* __restrict__ scw,
                               int M, int Nout, int K, int nby) {
    int nwg = gridDim.x;
    int orig = blockIdx.x;
    int q8 = nwg >> 3, r8 = nwg & 7;
    int xcd = orig & 7, idx = orig >> 3;
    int wgid = (xcd < r8 ? xcd * (q8 + 1) : r8 * (q8 + 1) + (xcd - r8) * q8) + idx;
    int by = wgid % nby;
    int bx = wgid / nby;

    __shared__ alignas(16) u16 lA[2][BM * BK];
    __shared__ alignas(16) u16 lB[2][BN * BK];
    int tid = threadIdx.x;
    int lane = tid & 63;
    int wv = tid >> 6;
    int m0 = bx * BM;
    int n0 = by * BN;
    int wrow = (wv >> 1) * 64;
    int wcol = (wv & 1) * 64;

    f32x4 acc[4][4];
#pragma unroll
    for (int i = 0; i < 4; i++)
#pragma unroll
        for (int j = 0; j < 4; j++) acc[i][j] = (f32x4){0.f, 0.f, 0.f, 0.f};

    int srow = lane >> 2;
    int scol = (lane & 3) * 8;
    int arow0 = m0 + wv * 16 + srow;        if (arow0 >= M) arow0 = M - 1;
    int arow1 = m0 + 64 + wv * 16 + srow;   if (arow1 >= M) arow1 = M - 1;
    const u16* gA0 = A + (size_t)arow0 * K + scol;
    const u16* gA1 = A + (size_t)arow1 * K + scol;
    const u16* gB0 = W + (size_t)(n0 + wv * 16 + srow) * K + scol;
    const u16* gB1 = W + (size_t)(n0 + 64 + wv * 16 + srow) * K + scol;
    int la0 = (wv * 16) * BK;
    int la1 = (64 + wv * 16) * BK;

    int fr = lane & 15;
    int kq = (lane >> 4) * 8;
    int nt = K / BK;

    gload16(gA0, lA[0] + la0);
    gload16(gA1, lA[0] + la1);
    gload16(gB0, lB[0] + la0);
    gload16(gB1, lB[0] + la1);
    __syncthreads();

    for (int t = 0; t < nt; t++) {
        int cur = t & 1;
        if (t + 1 < nt) {
            int kt = (t + 1) * BK;
            gload16(gA0 + kt, lA[cur ^ 1] + la0);
            gload16(gA1 + kt, lA[cur ^ 1] + la1);
            gload16(gB0 + kt, lB[cur ^ 1] + la0);
            gload16(gB1 + kt, lB[cur ^ 1] + la1);
        }
        bf16x8 af[4], bfr[4];
#pragma unroll
        for (int m = 0; m < 4; m++)
            af[m] = *(const bf16x8*)(lA[cur] + (wrow + m * 16 + fr) * BK + kq);
#pragma unroll
        for (int nf = 0; nf < 4; nf++)
            bfr[nf] = *(const bf16x8*)(lB[cur] + (wcol + nf * 16 + fr) * BK + kq);
#pragma unroll
        for (int m = 0; m < 4; m++)
#pragma unroll
            for (int nf = 0; nf < 4; nf++)
                acc[m][nf] = __builtin_amdgcn_mfma_f32_16x16x32_bf16(af[m], bfr[nf], acc[m][nf], 0, 0, 0);
        __syncthreads();
    }

    // epilogue: C/D layout col=lane&15, row=(lane>>4)*4+reg
    int r0 = (lane >> 4) * 4;
    if constexpr (MODE == 0) {
#pragma unroll
        for (int m = 0; m < 4; m++) {
#pragma unroll
            for (int nf = 0; nf < 4; nf++) {
                int gc = n0 + wcol + nf * 16 + fr;
                float bv = ACT ? bias[gc] : 0.f;
#pragma unroll
                for (int r = 0; r < 4; r++) {
                    int gr = m0 + wrow + m * 16 + r0 + r;
                    if (gr < M) {
                        float v = acc[m][nf][r] + bv;
                        if constexpr (ACT) v = (v >= 0.f) ? v : 0.2f * v;
                        C[(size_t)gr * Nout + gc] = f2b(v);
                    }
                }
            }
        }
    } else {
        // fused int8 quant: per-(row, 64col) scale via 16-lane shfl reduce
        int nch = Nout >> 6;
        int chunk = (n0 + wcol) >> 6;
#pragma unroll
        for (int m = 0; m < 4; m++) {
            float v[4][4];
#pragma unroll
            for (int nf = 0; nf < 4; nf++) {
                float bv = ACT ? bias[n0 + wcol + nf * 16 + fr] : 0.f;
#pragma unroll
                for (int r = 0; r < 4; r++) {
                    float tv = acc[m][nf][r] + bv;
                    if constexpr (ACT) tv = (tv >= 0.f) ? tv : 0.2f * tv;
                    v[nf][r] = tv;
                }
            }
#pragma unroll
            for (int r = 0; r < 4; r++) {
                float amax = fmaxf(fmaxf(fabsf(v[0][r]), fabsf(v[1][r])),
                                   fmaxf(fabsf(v[2][r]), fabsf(v[3][r])));
#pragma unroll
                for (int d = 1; d < 16; d <<= 1) amax = fmaxf(amax, __shfl_xor(amax, d));
                int gr = m0 + wrow + m * 16 + r0 + r;
                float scale = (amax > 0.f) ? 127.f / amax : 0.f;
                if (gr < M) {
#pragma unroll
                    for (int nf = 0; nf < 4; nf++) {
                        int qv = (int)rintf(v[nf][r] * scale);
                        qc[(size_t)gr * Nout + n0 + wcol + nf * 16 + fr] = (signed char)qv;
                    }
                    if (fr == 0)
                        scw[(size_t)gr * nch + chunk] = (amax > 0.f) ? amax / 127.f : 0.f;
                }
            }
        }
    }
}

// ---------------- final fc ----------------
__global__ void fc_kernel(const float* __restrict__ x3, const int* __restrict__ cidx,
                          const float* __restrict__ W, const float* __restrict__ b,
                          float* __restrict__ out, int C, int F) {
    __shared__ float xr[256];
    int k = blockIdx.x;
    int node = cidx[k];
    int tid = threadIdx.x;
    xr[tid] = x3[(size_t)node * C + tid];
    __syncthreads();
    for (int f = tid; f < F; f += 256) {
        const float4* wr = (const float4*)(W + (size_t)f * C);
        float acc = 0.f;
#pragma unroll 8
        for (int c4 = 0; c4 < C / 4; ++c4) {
            float4 wv = wr[c4];
            acc += xr[c4 * 4 + 0] * wv.x + xr[c4 * 4 + 1] * wv.y +
                   xr[c4 * 4 + 2] * wv.z + xr[c4 * 4 + 3] * wv.w;
        }
        out[(size_t)k * F + f] = acc + b[f];
    }
}

extern "C" void kernel_launch(void* const* d_in, const int* in_sizes, int n_in,
                              void* d_out, int out_size, void* d_ws, size_t ws_size,
                              hipStream_t stream) {
    const float* x    = (const float*)d_in[0];
    const int*   ei   = (const int*)d_in[1];
    const int*   cidx = (const int*)d_in[2];
    const float* W1   = (const float*)d_in[3];
    const float* b1   = (const float*)d_in[4];
    const float* eps1 = (const float*)d_in[5];
    const float* W2   = (const float*)d_in[6];
    const float* b2   = (const float*)d_in[7];
    const float* eps2 = (const float*)d_in[8];
    const float* W3   = (const float*)d_in[9];
    const float* b3   = (const float*)d_in[10];
    const float* eps3 = (const float*)d_in[11];
    const float* Wfc  = (const float*)d_in[12];
    const float* bfc  = (const float*)d_in[13];

    const int F = 512, H = 512, Cc = 256;
    const int Nn = in_sizes[0] / F;   // 50000
    const int E  = in_sizes[1] / 2;   // 800000
    const int Kc = in_sizes[2];       // 1024

    // workspace layout
    const size_t SZ_T = (size_t)Nn * 512 * 2;   // 51.2 MB bf16 t buffer
    const size_t SZ_Q = (size_t)Nn * 512;       // 25.6 MB int8
    char* ws = (char*)d_ws;
    u16*   bufT = (u16*)ws;
    char*  qbuf = ws + SZ_T;
    float* sc   = (float*)(ws + SZ_T + SZ_Q);             // 50k x 8 scales (1.6MB)
    u16*   W1b  = (u16*)(ws + SZ_T + SZ_Q + (size_t)Nn * 32);
    u16*   W2b  = W1b + 262144;
    u16*   W3b  = W2b + 262144;
    int*   deg  = (int*)((char*)(W3b + 131072));
    int*   cnt  = deg + Nn;
    int*   rowp = cnt + Nn;
    int*   colx = rowp + Nn + 1;
    int*   bsum = colx + E;   // 256 ints

    // h2 lives in d_out's x3 region (50000*256 floats = 51.2MB), overwritten by agg3 at the end
    u16* hbuf = (u16*)d_out;

    int nbScan = (Nn + 255) / 256;  // 196

    hipMemsetAsync(deg, 0, 2 * (size_t)Nn * sizeof(int), stream);
    int prepBlocks = 13140 + (E + 255) / 256;
    prep_kernel<<<prepBlocks, 256, 0, stream>>>(x, qbuf, sc, W1, W1b, W2, W2b, W3, W3b,
                                                ei, deg, E);
    scanA_kernel<<<nbScan, 256, 0, stream>>>(deg, bsum, Nn);
    scanB_kernel<<<1, 256, 0, stream>>>(bsum, nbScan);
    scanC_kernel<<<nbScan, 256, 0, stream>>>(deg, bsum, rowp, Nn);
    fill_kernel<<<(E + 255) / 256, 256, 0, stream>>>(ei, rowp, cnt, colx, E);

    int aggBlocks = (Nn * 64 + 255) / 256;
    int nbx = (Nn + BM - 1) / BM;  // 391

    // layer 1: agg(qx) -> t1; gemm1 -> int8 h1 (fused quant)
    agg_q512<<<aggBlocks, 256, 0, stream>>>(qbuf, sc, bufT, rowp, colx, eps1, Nn);
    gemm_bt_kernel<2, true><<<nbx * 4, 256, 0, stream>>>(bufT, W1b, b1, nullptr, qbuf, sc,
                                                         Nn, H, F, 4);
    // layer 2: agg(qh1) -> t2; gemm2 -> bf16 h2 (feeds gemm3's MFMA A)
    agg_q512<<<aggBlocks, 256, 0, stream>>>(qbuf, sc, bufT, rowp, colx, eps2, Nn);
    gemm_bt_kernel<0, true><<<nbx * 4, 256, 0, stream>>>(bufT, W2b, b2, hbuf, nullptr, nullptr,
                                                         Nn, H, H, 4);
    // layer 3 commuted: g = h2 @ W3^T -> int8 qg (fused quant); then aggregate
    gemm_bt_kernel<2, false><<<nbx * 2, 256, 0, stream>>>(hbuf, W3b, nullptr, nullptr, qbuf, sc,
                                                          Nn, Cc, H, 2);
    float* x3 = (float*)d_out;
    agg3_q<<<aggBlocks, 256, 0, stream>>>(qbuf, sc, x3, rowp, colx, eps3, b3, Nn);

    // fc
    float* outp = x3 + (size_t)Nn * Cc;
    fc_kernel<<<Kc, 256, 0, stream>>>(x3, cidx, Wfc, bfc, outp, Cc, F);
}

// Round 8
// 483.186 us; speedup vs baseline: 1.6510x; 1.0772x over previous
//
#include <hip/hip_runtime.h>
#include <stdint.h>

typedef unsigned short u16;
typedef __attribute__((ext_vector_type(4))) unsigned short u16x4;
typedef __attribute__((ext_vector_type(8))) unsigned short u16x8;
typedef __attribute__((ext_vector_type(8))) short bf16x8;
typedef __attribute__((ext_vector_type(4))) float f32x4;
typedef __attribute__((ext_vector_type(4))) float f4v;
typedef __attribute__((ext_vector_type(4))) int i32x4;

__device__ __forceinline__ float b2f(u16 u) {
    union { unsigned u; float f; } c; c.u = ((unsigned)u) << 16; return c.f;
}
__device__ __forceinline__ u16 f2b(float f) {
    union { float f; unsigned u; } c; c.f = f;
    unsigned r = c.u + 0x7fffu + ((c.u >> 16) & 1u);
    return (u16)(r >> 16);
}

// async global->LDS 16B
__device__ __forceinline__ void gload16(const void* g, void* l) {
    __builtin_amdgcn_global_load_lds(
        (const __attribute__((address_space(1))) unsigned int*)g,
        (__attribute__((address_space(3))) unsigned int*)l, 16, 0, 0);
}

__device__ __forceinline__ void cvt4(const float* in, u16* out, int idx) {
    f4v v = ((const f4v*)in)[idx];
    u16x4 o;
    o[0] = f2b(v[0]); o[1] = f2b(v[1]); o[2] = f2b(v[2]); o[3] = f2b(v[3]);
    ((u16x4*)out)[idx] = o;
}

// dequant 8 int8 (packed int2) with scale s, accumulate
__device__ __forceinline__ void dq_acc(int2 d, float s, float* acc) {
#pragma unroll
    for (int j = 0; j < 4; j++) acc[j]     += s * (float)(signed char)(d.x >> (8 * j));
#pragma unroll
    for (int j = 0; j < 4; j++) acc[j + 4] += s * (float)(signed char)(d.y >> (8 * j));
}
__device__ __forceinline__ void dq_acc4(int d, float s, float* acc) {
#pragma unroll
    for (int j = 0; j < 4; j++) acc[j] += s * (float)(signed char)(d >> (8 * j));
}

// quantize one 512-float row to int8 with per-row scale (wave per row)
__device__ __forceinline__ void qrow512(const float* __restrict__ src, char* __restrict__ dst,
                                        float* __restrict__ srow, int r, int lane) {
    const f4v* p = (const f4v*)(src + (size_t)r * 512) + lane * 2;
    f4v v0 = p[0], v1 = p[1];
    float m = 0.f;
#pragma unroll
    for (int j = 0; j < 4; j++) { m = fmaxf(m, fabsf(v0[j])); m = fmaxf(m, fabsf(v1[j])); }
#pragma unroll
    for (int d = 1; d < 64; d <<= 1) m = fmaxf(m, __shfl_xor(m, d));
    float qs = (m > 0.f) ? 127.f / m : 0.f;
    int lo = 0, hi = 0;
#pragma unroll
    for (int j = 0; j < 4; j++) { int q = (int)rintf(v0[j] * qs); lo |= (q & 0xFF) << (8 * j); }
#pragma unroll
    for (int j = 0; j < 4; j++) { int q = (int)rintf(v1[j] * qs); hi |= (q & 0xFF) << (8 * j); }
    ((int2*)(dst + (size_t)r * 512))[lane] = make_int2(lo, hi);
    if (lane == 0) srow[r] = (m > 0.f) ? m / 127.f : 0.f;
}

// ---------------- merged preamble ----------------
// [0,12500): x -> int8 per-64chunk scales | [12500,12628) W1 int8/row | [12628,12756) W2 int8/row
// [12756,12884) W3 bf16 | [12884,16009) edge count
__global__ void prep_kernel(const float* __restrict__ x, char* __restrict__ qx,
                            float* __restrict__ xs,
                            const float* __restrict__ W1, char* __restrict__ W1q, float* __restrict__ ws1,
                            const float* __restrict__ W2, char* __restrict__ W2q, float* __restrict__ ws2,
                            const float* __restrict__ W3, u16* __restrict__ W3b,
                            const int* __restrict__ ei, int* __restrict__ deg, int E) {
    int b = blockIdx.x;
    int tid = threadIdx.x;
    if (b < 12500) {
        int w = b * 4 + (tid >> 6);
        int lane = tid & 63;
        const f4v* xr = (const f4v*)(x + (size_t)w * 512) + lane * 2;
        f4v v0 = xr[0], v1 = xr[1];
        float m = 0.f;
#pragma unroll
        for (int j = 0; j < 4; j++) { m = fmaxf(m, fabsf(v0[j])); m = fmaxf(m, fabsf(v1[j])); }
#pragma unroll
        for (int d = 1; d < 8; d <<= 1) m = fmaxf(m, __shfl_xor(m, d));
        float scale = (m > 0.f) ? 127.f / m : 0.f;
        int lo = 0, hi = 0;
#pragma unroll
        for (int j = 0; j < 4; j++) { int q = (int)rintf(v0[j] * scale); lo |= (q & 0xFF) << (8 * j); }
#pragma unroll
        for (int j = 0; j < 4; j++) { int q = (int)rintf(v1[j] * scale); hi |= (q & 0xFF) << (8 * j); }
        ((int2*)(qx + (size_t)w * 512))[lane] = make_int2(lo, hi);
        if ((lane & 7) == 0) xs[w * 8 + (lane >> 3)] = (m > 0.f) ? m / 127.f : 0.f;
    } else if (b < 12628) {
        qrow512(W1, W1q, ws1, (b - 12500) * 4 + (tid >> 6), tid & 63);
    } else if (b < 12756) {
        qrow512(W2, W2q, ws2, (b - 12628) * 4 + (tid >> 6), tid & 63);
    } else if (b < 12884) {
        cvt4(W3, W3b, (b - 12756) * 256 + tid);
    } else {
        int e = (b - 12884) * 256 + tid;
        if (e < E) atomicAdd(&deg[ei[E + e]], 1);
    }
}

// ---------------- hierarchical scan ----------------
__global__ void scanA_kernel(const int* __restrict__ deg, int* __restrict__ bsum, int n) {
    __shared__ int sm[256];
    int tid = threadIdx.x;
    int i = blockIdx.x * 256 + tid;
    sm[tid] = (i < n) ? deg[i] : 0;
    __syncthreads();
#pragma unroll
    for (int off = 128; off > 0; off >>= 1) {
        if (tid < off) sm[tid] += sm[tid + off];
        __syncthreads();
    }
    if (tid == 0) bsum[blockIdx.x] = sm[0];
}

__global__ void scanB_kernel(int* __restrict__ bsum, int nb) {
    __shared__ int sm[256];
    int tid = threadIdx.x;
    int v = (tid < nb) ? bsum[tid] : 0;
    sm[tid] = v;
    __syncthreads();
#pragma unroll
    for (int off = 1; off < 256; off <<= 1) {
        int t = (tid >= off) ? sm[tid - off] : 0;
        __syncthreads();
        sm[tid] += t;
        __syncthreads();
    }
    if (tid < nb) bsum[tid] = sm[tid] - v;
}

__global__ void scanC_kernel(const int* __restrict__ deg, const int* __restrict__ bsum,
                             int* __restrict__ rowp, int n) {
    __shared__ int sm[256];
    int tid = threadIdx.x;
    int b = blockIdx.x;
    int i = b * 256 + tid;
    int v = (i < n) ? deg[i] : 0;
    sm[tid] = v;
    __syncthreads();
#pragma unroll
    for (int off = 1; off < 256; off <<= 1) {
        int t = (tid >= off) ? sm[tid - off] : 0;
        __syncthreads();
        sm[tid] += t;
        __syncthreads();
    }
    if (i < n) rowp[i] = bsum[b] + sm[tid] - v;
    if (i == n - 1) rowp[n] = bsum[b] + sm[tid];
}

__global__ void fill_kernel(const int* __restrict__ ei, const int* __restrict__ rowp,
                            int* __restrict__ cnt, int* __restrict__ col, int E) {
    int e = blockIdx.x * blockDim.x + threadIdx.x;
    if (e < E) {
        int dst = ei[E + e];
        int pos = atomicAdd(&cnt[dst], 1);
        col[rowp[dst] + pos] = ei[e];
    }
}

// ---------------- int8 GIN aggregation (512 feats) -> int8 t + per-row scale ----------------
__global__ void agg_q512(const char* __restrict__ q, const float* __restrict__ sc,
                         char* __restrict__ tq, float* __restrict__ tsc,
                         const int* __restrict__ rowp, const int* __restrict__ col,
                         const float* __restrict__ epsp, int N) {
    int w = (blockIdx.x * blockDim.x + threadIdx.x) >> 6;
    if (w >= N) return;
    int lane = threadIdx.x & 63;
    float coef = 2.0f + epsp[0];
    const int2* base = (const int2*)q;
    int ch = lane >> 3;
    float acc[8];
#pragma unroll
    for (int j = 0; j < 8; j++) acc[j] = 0.f;
    dq_acc(base[(size_t)w * 64 + lane], coef * sc[w * 8 + ch], acc);
    int p = rowp[w], e = rowp[w + 1];
    for (; p + 2 <= e; p += 2) {
        int s0 = __builtin_amdgcn_readfirstlane(col[p]);
        int s1 = __builtin_amdgcn_readfirstlane(col[p + 1]);
        int2 v0 = base[(size_t)s0 * 64 + lane];
        int2 v1 = base[(size_t)s1 * 64 + lane];
        float f0 = sc[s0 * 8 + ch];
        float f1 = sc[s1 * 8 + ch];
        dq_acc(v0, f0, acc);
        dq_acc(v1, f1, acc);
    }
    if (p < e) {
        int s0 = __builtin_amdgcn_readfirstlane(col[p]);
        dq_acc(base[(size_t)s0 * 64 + lane], sc[s0 * 8 + ch], acc);
    }
    // quantize t row to int8 with per-row scale (feeds i8 MFMA GEMM)
    float m = 0.f;
#pragma unroll
    for (int j = 0; j < 8; j++) m = fmaxf(m, fabsf(acc[j]));
#pragma unroll
    for (int d = 1; d < 64; d <<= 1) m = fmaxf(m, __shfl_xor(m, d));
    float qs = (m > 0.f) ? 127.f / m : 0.f;
    int lo = 0, hi = 0;
#pragma unroll
    for (int j = 0; j < 4; j++) { int qv = (int)rintf(acc[j] * qs); lo |= (qv & 0xFF) << (8 * j); }
#pragma unroll
    for (int j = 0; j < 4; j++) { int qv = (int)rintf(acc[j + 4] * qs); hi |= (qv & 0xFF) << (8 * j); }
    ((int2*)(tq + (size_t)w * 512))[lane] = make_int2(lo, hi);
    if (lane == 0) tsc[w] = (m > 0.f) ? m / 127.f : 0.f;
}

// ---------------- int8 layer-3 aggregation (256 feats, 4-chunk scales) -> fp32 ----------------
__global__ void agg3_q(const char* __restrict__ q, const float* __restrict__ sc,
                       float* __restrict__ out, const int* __restrict__ rowp,
                       const int* __restrict__ col, const float* __restrict__ epsp,
                       const float* __restrict__ bias, int N) {
    int w = (blockIdx.x * blockDim.x + threadIdx.x) >> 6;
    if (w >= N) return;
    int lane = threadIdx.x & 63;
    float coef = 2.0f + epsp[0];
    const int* base = (const int*)q;
    int ch = lane >> 4;
    f4v bv = *(const f4v*)(bias + lane * 4);
    float acc[4];
#pragma unroll
    for (int j = 0; j < 4; j++) acc[j] = 0.f;
    dq_acc4(base[(size_t)w * 64 + lane], coef * sc[w * 4 + ch], acc);
    int p = rowp[w], e = rowp[w + 1];
    for (; p + 2 <= e; p += 2) {
        int s0 = __builtin_amdgcn_readfirstlane(col[p]);
        int s1 = __builtin_amdgcn_readfirstlane(col[p + 1]);
        int v0 = base[(size_t)s0 * 64 + lane];
        int v1 = base[(size_t)s1 * 64 + lane];
        float f0 = sc[s0 * 4 + ch];
        float f1 = sc[s1 * 4 + ch];
        dq_acc4(v0, f0, acc);
        dq_acc4(v1, f1, acc);
    }
    if (p < e) {
        int s0 = __builtin_amdgcn_readfirstlane(col[p]);
        dq_acc4(base[(size_t)s0 * 64 + lane], sc[s0 * 4 + ch], acc);
    }
    f4v o;
#pragma unroll
    for (int j = 0; j < 4; j++) {
        float v = acc[j] + bv[j];
        o[j] = (v >= 0.f) ? v : 0.2f * v;
    }
    *(f4v*)(out + (size_t)w * 256 + lane * 4) = o;
}

// ---------------- int8 MFMA GEMM (i32 accum over full K, scale-once epilogue) ----------------
// C = leaky(A_i8[M][K]*sA[row] @ (W_i8[Nout][K]*sW[outrow])^T + bias)
// 128x128 tile, BK=64 (one mfma_i32_16x16x64_i8 per frag per step), 2-phase dbuf.
// MODE 1: bf16 out; MODE 2: int8 + per-(row,64col) scale out.
template <int MODE>
__launch_bounds__(256)
__global__ void gemm_i8_kernel(const char* __restrict__ A, const float* __restrict__ sA,
                               const char* __restrict__ Wq, const float* __restrict__ sW,
                               const float* __restrict__ bias, u16* __restrict__ C,
                               char* __restrict__ qc, float* __restrict__ scw,
                               int M, int Nout, int K, int nby) {
    int nwg = gridDim.x;
    int orig = blockIdx.x;
    int q8 = nwg >> 3, r8 = nwg & 7;
    int xcd = orig & 7, idx = orig >> 3;
    int wgid = (xcd < r8 ? xcd * (q8 + 1) : r8 * (q8 + 1) + (xcd - r8) * q8) + idx;
    int by = wgid % nby;
    int bx = wgid / nby;

    __shared__ alignas(16) char lA[2][128 * 64];
    __shared__ alignas(16) char lB[2][128 * 64];
    int tid = threadIdx.x;
    int lane = tid & 63;
    int wv = tid >> 6;
    int m0 = bx * 128;
    int n0 = by * 128;
    int wrow = (wv >> 1) * 64;
    int wcol = (wv & 1) * 64;

    i32x4 acc[4][4];
#pragma unroll
    for (int i = 0; i < 4; i++)
#pragma unroll
        for (int j = 0; j < 4; j++) acc[i][j] = (i32x4){0, 0, 0, 0};

    // staging: 64B rows; lane covers row lane>>2, 16B slot lane&3
    int srow = lane >> 2;
    int scol = (lane & 3) * 16;
    int arow0 = m0 + wv * 16 + srow;        if (arow0 >= M) arow0 = M - 1;
    int arow1 = m0 + 64 + wv * 16 + srow;   if (arow1 >= M) arow1 = M - 1;
    const char* gA0 = A + (size_t)arow0 * K + scol;
    const char* gA1 = A + (size_t)arow1 * K + scol;
    const char* gB0 = Wq + (size_t)(n0 + wv * 16 + srow) * K + scol;
    const char* gB1 = Wq + (size_t)(n0 + 64 + wv * 16 + srow) * K + scol;
    int la0 = (wv * 16) * 64;
    int la1 = (64 + wv * 16) * 64;

    int fr = lane & 15;
    int kq = (lane >> 4) * 16;  // byte offset of this lane's K-slice
    int nt = K / 64;

    gload16(gA0, lA[0] + la0);
    gload16(gA1, lA[0] + la1);
    gload16(gB0, lB[0] + la0);
    gload16(gB1, lB[0] + la1);
    __syncthreads();

    for (int t = 0; t < nt; t++) {
        int cur = t & 1;
        if (t + 1 < nt) {
            int kt = (t + 1) * 64;
            gload16(gA0 + kt, lA[cur ^ 1] + la0);
            gload16(gA1 + kt, lA[cur ^ 1] + la1);
            gload16(gB0 + kt, lB[cur ^ 1] + la0);
            gload16(gB1 + kt, lB[cur ^ 1] + la1);
        }
        i32x4 af[4], bf[4];
#pragma unroll
        for (int m = 0; m < 4; m++)
            af[m] = *(const i32x4*)(lA[cur] + (wrow + m * 16 + fr) * 64 + kq);
#pragma unroll
        for (int nf = 0; nf < 4; nf++)
            bf[nf] = *(const i32x4*)(lB[cur] + (wcol + nf * 16 + fr) * 64 + kq);
#pragma unroll
        for (int m = 0; m < 4; m++)
#pragma unroll
            for (int nf = 0; nf < 4; nf++)
                acc[m][nf] = __builtin_amdgcn_mfma_i32_16x16x64_i8(af[m], bf[nf], acc[m][nf], 0, 0, 0);
        __syncthreads();
    }

    // epilogue: dequant once (i32 * sA[row] * sW[col]), bias+leaky, store
    int r0 = (lane >> 4) * 4;
#pragma unroll
    for (int m = 0; m < 4; m++) {
        float sa[4];
#pragma unroll
        for (int r = 0; r < 4; r++) {
            int gr = m0 + wrow + m * 16 + r0 + r;
            sa[r] = sA[gr < M ? gr : M - 1];
        }
        float v[4][4];
#pragma unroll
        for (int nf = 0; nf < 4; nf++) {
            int gc = n0 + wcol + nf * 16 + fr;
            float swv = sW[gc];
            float bv = bias[gc];
#pragma unroll
            for (int r = 0; r < 4; r++) {
                float tv = (float)acc[m][nf][r] * sa[r] * swv + bv;
                v[nf][r] = (tv >= 0.f) ? tv : 0.2f * tv;
            }
        }
        if constexpr (MODE == 1) {
#pragma unroll
            for (int nf = 0; nf < 4; nf++) {
                int gc = n0 + wcol + nf * 16 + fr;
#pragma unroll
                for (int r = 0; r < 4; r++) {
                    int gr = m0 + wrow + m * 16 + r0 + r;
                    if (gr < M) C[(size_t)gr * Nout + gc] = f2b(v[nf][r]);
                }
            }
        } else {
            int nch = Nout >> 6;
            int chunk = (n0 + wcol) >> 6;
#pragma unroll
            for (int r = 0; r < 4; r++) {
                float amax = fmaxf(fmaxf(fabsf(v[0][r]), fabsf(v[1][r])),
                                   fmaxf(fabsf(v[2][r]), fabsf(v[3][r])));
#pragma unroll
                for (int d = 1; d < 16; d <<= 1) amax = fmaxf(amax, __shfl_xor(amax, d));
                int gr = m0 + wrow + m * 16 + r0 + r;
                float scale = (amax > 0.f) ? 127.f / amax : 0.f;
                if (gr < M) {
#pragma unroll
                    for (int nf = 0; nf < 4; nf++) {
                        int qv = (int)rintf(v[nf][r] * scale);
                        qc[(size_t)gr * Nout + n0 + wcol + nf * 16 + fr] = (signed char)qv;
                    }
                    if (fr == 0)
                        scw[(size_t)gr * nch + chunk] = (amax > 0.f) ? amax / 127.f : 0.f;
                }
            }
        }
    }
}

// ---------------- bf16 MFMA GEMM (layer 3 only): 2-phase dbuf, fused int8-quant out ----------------
#define BM 128
#define BN 128
#define BK 32

__launch_bounds__(256)
__global__ void gemm_bt_kernel(const u16* __restrict__ A, const u16* __restrict__ W,
                               char* __restrict__ qc, float* __restrict__ scw,
                               int M, int Nout, int K, int nby) {
    int nwg = gridDim.x;
    int orig = blockIdx.x;
    int q8 = nwg >> 3, r8 = nwg & 7;
    int xcd = orig & 7, idx = orig >> 3;
    int wgid = (xcd < r8 ? xcd * (q8 + 1) : r8 * (q8 + 1) + (xcd - r8) * q8) + idx;
    int by = wgid % nby;
    int bx = wgid / nby;

    __shared__ alignas(16) u16 lA[2][BM * BK];
    __shared__ alignas(16) u16 lB[2][BN * BK];
    int tid = threadIdx.x;
    int lane = tid & 63;
    int wv = tid >> 6;
    int m0 = bx * BM;
    int n0 = by * BN;
    int wrow = (wv >> 1) * 64;
    int wcol = (wv & 1) * 64;

    f32x4 acc[4][4];
#pragma unroll
    for (int i = 0; i < 4; i++)
#pragma unroll
        for (int j = 0; j < 4; j++) acc[i][j] = (f32x4){0.f, 0.f, 0.f, 0.f};

    int srow = lane >> 2;
    int scol = (lane & 3) * 8;
    int arow0 = m0 + wv * 16 + srow;        if (arow0 >= M) arow0 = M - 1;
    int arow1 = m0 + 64 + wv * 16 + srow;   if (arow1 >= M) arow1 = M - 1;
    const u16* gA0 = A + (size_t)arow0 * K + scol;
    const u16* gA1 = A + (size_t)arow1 * K + scol;
    const u16* gB0 = W + (size_t)(n0 + wv * 16 + srow) * K + scol;
    const u16* gB1 = W + (size_t)(n0 + 64 + wv * 16 + srow) * K + scol;
    int la0 = (wv * 16) * BK;
    int la1 = (64 + wv * 16) * BK;

    int fr = lane & 15;
    int kq = (lane >> 4) * 8;
    int nt = K / BK;

    gload16(gA0, lA[0] + la0);
    gload16(gA1, lA[0] + la1);
    gload16(gB0, lB[0] + la0);
    gload16(gB1, lB[0] + la1);
    __syncthreads();

    for (int t = 0; t < nt; t++) {
        int cur = t & 1;
        if (t + 1 < nt) {
            int kt = (t + 1) * BK;
            gload16(gA0 + kt, lA[cur ^ 1] + la0);
            gload16(gA1 + kt, lA[cur ^ 1] + la1);
            gload16(gB0 + kt, lB[cur ^ 1] + la0);
            gload16(gB1 + kt, lB[cur ^ 1] + la1);
        }
        bf16x8 af[4], bfr[4];
#pragma unroll
        for (int m = 0; m < 4; m++)
            af[m] = *(const bf16x8*)(lA[cur] + (wrow + m * 16 + fr) * BK + kq);
#pragma unroll
        for (int nf = 0; nf < 4; nf++)
            bfr[nf] = *(const bf16x8*)(lB[cur] + (wcol + nf * 16 + fr) * BK + kq);
#pragma unroll
        for (int m = 0; m < 4; m++)
#pragma unroll
            for (int nf = 0; nf < 4; nf++)
                acc[m][nf] = __builtin_amdgcn_mfma_f32_16x16x32_bf16(af[m], bfr[nf], acc[m][nf], 0, 0, 0);
        __syncthreads();
    }

    // fused int8-quant epilogue (no bias/act — layer-3 commuted GEMM)
    int r0 = (lane >> 4) * 4;
    int nch = Nout >> 6;
    int chunk = (n0 + wcol) >> 6;
#pragma unroll
    for (int m = 0; m < 4; m++) {
        float v[4][4];
#pragma unroll
        for (int nf = 0; nf < 4; nf++)
#pragma unroll
            for (int r = 0; r < 4; r++) v[nf][r] = acc[m][nf][r];
#pragma unroll
        for (int r = 0; r < 4; r++) {
            float amax = fmaxf(fmaxf(fabsf(v[0][r]), fabsf(v[1][r])),
                               fmaxf(fabsf(v[2][r]), fabsf(v[3][r])));
#pragma unroll
            for (int d = 1; d < 16; d <<= 1) amax = fmaxf(amax, __shfl_xor(amax, d));
            int gr = m0 + wrow + m * 16 + r0 + r;
            float scale = (amax > 0.f) ? 127.f / amax : 0.f;
            if (gr < M) {
#pragma unroll
                for (int nf = 0; nf < 4; nf++) {
                    int qv = (int)rintf(v[nf][r] * scale);
                    qc[(size_t)gr * Nout + n0 + wcol + nf * 16 + fr] = (signed char)qv;
                }
                if (fr == 0)
                    scw[(size_t)gr * nch + chunk] = (amax > 0.f) ? amax / 127.f : 0.f;
            }
        }
    }
}

// ---------------- final fc ----------------
__global__ void fc_kernel(const float* __restrict__ x3, const int* __restrict__ cidx,
                          const float* __restrict__ W, const float* __restrict__ b,
                          float* __restrict__ out, int C, int F) {
    __shared__ float xr[256];
    int k = blockIdx.x;
    int node = cidx[k];
    int tid = threadIdx.x;
    xr[tid] = x3[(size_t)node * C + tid];
    __syncthreads();
    for (int f = tid; f < F; f += 256) {
        const float4* wr = (const float4*)(W + (size_t)f * C);
        float acc = 0.f;
#pragma unroll 8
        for (int c4 = 0; c4 < C / 4; ++c4) {
            float4 wv = wr[c4];
            acc += xr[c4 * 4 + 0] * wv.x + xr[c4 * 4 + 1] * wv.y +
                   xr[c4 * 4 + 2] * wv.z + xr[c4 * 4 + 3] * wv.w;
        }
        out[(size_t)k * F + f] = acc + b[f];
    }
}

extern "C" void kernel_launch(void* const* d_in, const int* in_sizes, int n_in,
                              void* d_out, int out_size, void* d_ws, size_t ws_size,
                              hipStream_t stream) {
    const float* x    = (const float*)d_in[0];
    const int*   ei   = (const int*)d_in[1];
    const int*   cidx = (const int*)d_in[2];
    const float* W1   = (const float*)d_in[3];
    const float* b1   = (const float*)d_in[4];
    const float* eps1 = (const float*)d_in[5];
    const float* W2   = (const float*)d_in[6];
    const float* b2   = (const float*)d_in[7];
    const float* eps2 = (const float*)d_in[8];
    const float* W3   = (const float*)d_in[9];
    const float* b3   = (const float*)d_in[10];
    const float* eps3 = (const float*)d_in[11];
    const float* Wfc  = (const float*)d_in[12];
    const float* bfc  = (const float*)d_in[13];

    const int F = 512, H = 512, Cc = 256;
    const int Nn = in_sizes[0] / F;   // 50000
    const int E  = in_sizes[1] / 2;   // 800000
    const int Kc = in_sizes[2];       // 1024

    // workspace layout
    const size_t SZ_Q = (size_t)Nn * 512;  // 25.6 MB int8 plane
    char* ws = (char*)d_ws;
    char*  tq   = ws;                              // int8 t (agg output)
    char*  qbuf = ws + SZ_Q;                       // int8 h / g (gather source)
    float* tsc  = (float*)(ws + 2 * SZ_Q);         // per-row t scales
    float* sc   = tsc + Nn;                        // per-(row,64chunk) gather scales (Nn*8)
    char*  W1q  = (char*)(sc + (size_t)Nn * 8);
    float* ws1  = (float*)(W1q + 262144);
    char*  W2q  = (char*)(ws1 + 512);
    float* ws2  = (float*)(W2q + 262144);
    u16*   W3b  = (u16*)(ws2 + 512);
    int*   deg  = (int*)((char*)W3b + 262144);
    int*   cnt  = deg + Nn;
    int*   rowp = cnt + Nn;
    int*   colx = rowp + Nn + 1;
    int*   bsum = colx + E;

    // h2 (bf16) lives in d_out's x3 region; overwritten by agg3 at the end
    u16* hbuf = (u16*)d_out;

    int nbScan = (Nn + 255) / 256;

    hipMemsetAsync(deg, 0, 2 * (size_t)Nn * sizeof(int), stream);
    int prepBlocks = 12884 + (E + 255) / 256;
    prep_kernel<<<prepBlocks, 256, 0, stream>>>(x, qbuf, sc, W1, W1q, ws1, W2, W2q, ws2,
                                                W3, W3b, ei, deg, E);
    scanA_kernel<<<nbScan, 256, 0, stream>>>(deg, bsum, Nn);
    scanB_kernel<<<1, 256, 0, stream>>>(bsum, nbScan);
    scanC_kernel<<<nbScan, 256, 0, stream>>>(deg, bsum, rowp, Nn);
    fill_kernel<<<(E + 255) / 256, 256, 0, stream>>>(ei, rowp, cnt, colx, E);

    int aggBlocks = (Nn * 64 + 255) / 256;
    int nbx = (Nn + 127) / 128;  // 391

    // layer 1: agg(qx) -> int8 t1; i8-GEMM -> int8 h1 (fused quant, 8 chunk scales)
    agg_q512<<<aggBlocks, 256, 0, stream>>>(qbuf, sc, tq, tsc, rowp, colx, eps1, Nn);
    gemm_i8_kernel<2><<<nbx * 4, 256, 0, stream>>>(tq, tsc, W1q, ws1, b1, nullptr,
                                                   qbuf, sc, Nn, H, F, 4);
    // layer 2: agg(qh1) -> int8 t2; i8-GEMM -> bf16 h2
    agg_q512<<<aggBlocks, 256, 0, stream>>>(qbuf, sc, tq, tsc, rowp, colx, eps2, Nn);
    gemm_i8_kernel<1><<<nbx * 4, 256, 0, stream>>>(tq, tsc, W2q, ws2, b2, hbuf,
                                                   nullptr, nullptr, Nn, H, H, 4);
    // layer 3 commuted: g = h2 @ W3^T (bf16 MFMA) -> int8 qg; then aggregate
    gemm_bt_kernel<<<nbx * 2, 256, 0, stream>>>(hbuf, W3b, qbuf, sc, Nn, Cc, H, 2);
    float* x3 = (float*)d_out;
    agg3_q<<<aggBlocks, 256, 0, stream>>>(qbuf, sc, x3, rowp, colx, eps3, b3, Nn);

    // fc
    float* outp = x3 + (size_t)Nn * Cc;
    fc_kernel<<<Kc, 256, 0, stream>>>(x3, cidx, Wfc, bfc, outp, Cc, F);
}

// Round 9
// 451.499 us; speedup vs baseline: 1.7668x; 1.0702x over previous
//
#include <hip/hip_runtime.h>
#include <stdint.h>

typedef unsigned short u16;
typedef __attribute__((ext_vector_type(4))) unsigned short u16x4;
typedef __attribute__((ext_vector_type(8))) unsigned short u16x8;
typedef __attribute__((ext_vector_type(8))) short bf16x8;
typedef __attribute__((ext_vector_type(4))) float f32x4;
typedef __attribute__((ext_vector_type(4))) float f4v;
typedef __attribute__((ext_vector_type(4))) int i32x4;

__device__ __forceinline__ float b2f(u16 u) {
    union { unsigned u; float f; } c; c.u = ((unsigned)u) << 16; return c.f;
}
__device__ __forceinline__ u16 f2b(float f) {
    union { float f; unsigned u; } c; c.f = f;
    unsigned r = c.u + 0x7fffu + ((c.u >> 16) & 1u);
    return (u16)(r >> 16);
}

// async global->LDS 16B
__device__ __forceinline__ void gload16(const void* g, void* l) {
    __builtin_amdgcn_global_load_lds(
        (const __attribute__((address_space(1))) unsigned int*)g,
        (__attribute__((address_space(3))) unsigned int*)l, 16, 0, 0);
}

__device__ __forceinline__ void cvt4(const float* in, u16* out, int idx) {
    f4v v = ((const f4v*)in)[idx];
    u16x4 o;
    o[0] = f2b(v[0]); o[1] = f2b(v[1]); o[2] = f2b(v[2]); o[3] = f2b(v[3]);
    ((u16x4*)out)[idx] = o;
}

// single-op byte extract+convert (VOP1, unsigned byte -> float, exact)
__device__ __forceinline__ float cvt_ub0(unsigned v) { float f; asm("v_cvt_f32_ubyte0 %0, %1" : "=v"(f) : "v"(v)); return f; }
__device__ __forceinline__ float cvt_ub1(unsigned v) { float f; asm("v_cvt_f32_ubyte1 %0, %1" : "=v"(f) : "v"(v)); return f; }
__device__ __forceinline__ float cvt_ub2(unsigned v) { float f; asm("v_cvt_f32_ubyte2 %0, %1" : "=v"(f) : "v"(v)); return f; }
__device__ __forceinline__ float cvt_ub3(unsigned v) { float f; asm("v_cvt_f32_ubyte3 %0, %1" : "=v"(f) : "v"(v)); return f; }

// biased-unsigned dequant accumulate: acc_j += s * (byte_j ^ 0x80)  [caller tracks csum
// = sum of s; final value = acc - 128*csum, exact since ub<=255]
__device__ __forceinline__ void dq_accu(int2 d, float s, float* acc) {
    unsigned ux = (unsigned)d.x ^ 0x80808080u;
    unsigned uy = (unsigned)d.y ^ 0x80808080u;
    acc[0] = fmaf(s, cvt_ub0(ux), acc[0]);
    acc[1] = fmaf(s, cvt_ub1(ux), acc[1]);
    acc[2] = fmaf(s, cvt_ub2(ux), acc[2]);
    acc[3] = fmaf(s, cvt_ub3(ux), acc[3]);
    acc[4] = fmaf(s, cvt_ub0(uy), acc[4]);
    acc[5] = fmaf(s, cvt_ub1(uy), acc[5]);
    acc[6] = fmaf(s, cvt_ub2(uy), acc[6]);
    acc[7] = fmaf(s, cvt_ub3(uy), acc[7]);
}
__device__ __forceinline__ void dq_accu4(int d, float s, float* acc) {
    unsigned ux = (unsigned)d ^ 0x80808080u;
    acc[0] = fmaf(s, cvt_ub0(ux), acc[0]);
    acc[1] = fmaf(s, cvt_ub1(ux), acc[1]);
    acc[2] = fmaf(s, cvt_ub2(ux), acc[2]);
    acc[3] = fmaf(s, cvt_ub3(ux), acc[3]);
}

// quantize one 512-float row to int8 with per-row scale (wave per row)
__device__ __forceinline__ void qrow512(const float* __restrict__ src, char* __restrict__ dst,
                                        float* __restrict__ srow, int r, int lane) {
    const f4v* p = (const f4v*)(src + (size_t)r * 512) + lane * 2;
    f4v v0 = p[0], v1 = p[1];
    float m = 0.f;
#pragma unroll
    for (int j = 0; j < 4; j++) { m = fmaxf(m, fabsf(v0[j])); m = fmaxf(m, fabsf(v1[j])); }
#pragma unroll
    for (int d = 1; d < 64; d <<= 1) m = fmaxf(m, __shfl_xor(m, d));
    float qs = (m > 0.f) ? 127.f / m : 0.f;
    int lo = 0, hi = 0;
#pragma unroll
    for (int j = 0; j < 4; j++) { int q = (int)rintf(v0[j] * qs); lo |= (q & 0xFF) << (8 * j); }
#pragma unroll
    for (int j = 0; j < 4; j++) { int q = (int)rintf(v1[j] * qs); hi |= (q & 0xFF) << (8 * j); }
    ((int2*)(dst + (size_t)r * 512))[lane] = make_int2(lo, hi);
    if (lane == 0) srow[r] = (m > 0.f) ? m / 127.f : 0.f;
}

// ---------------- merged preamble ----------------
// [0,12500): x -> int8 per-64chunk scales | [12500,12628) W1 int8/row | [12628,12756) W2 int8/row
// [12756,12884) W3 bf16 | [12884,16009) edge count
__global__ void prep_kernel(const float* __restrict__ x, char* __restrict__ qx,
                            float* __restrict__ xs,
                            const float* __restrict__ W1, char* __restrict__ W1q, float* __restrict__ ws1,
                            const float* __restrict__ W2, char* __restrict__ W2q, float* __restrict__ ws2,
                            const float* __restrict__ W3, u16* __restrict__ W3b,
                            const int* __restrict__ ei, int* __restrict__ deg, int E) {
    int b = blockIdx.x;
    int tid = threadIdx.x;
    if (b < 12500) {
        int w = b * 4 + (tid >> 6);
        int lane = tid & 63;
        const f4v* xr = (const f4v*)(x + (size_t)w * 512) + lane * 2;
        f4v v0 = xr[0], v1 = xr[1];
        float m = 0.f;
#pragma unroll
        for (int j = 0; j < 4; j++) { m = fmaxf(m, fabsf(v0[j])); m = fmaxf(m, fabsf(v1[j])); }
#pragma unroll
        for (int d = 1; d < 8; d <<= 1) m = fmaxf(m, __shfl_xor(m, d));
        float scale = (m > 0.f) ? 127.f / m : 0.f;
        int lo = 0, hi = 0;
#pragma unroll
        for (int j = 0; j < 4; j++) { int q = (int)rintf(v0[j] * scale); lo |= (q & 0xFF) << (8 * j); }
#pragma unroll
        for (int j = 0; j < 4; j++) { int q = (int)rintf(v1[j] * scale); hi |= (q & 0xFF) << (8 * j); }
        ((int2*)(qx + (size_t)w * 512))[lane] = make_int2(lo, hi);
        if ((lane & 7) == 0) xs[w * 8 + (lane >> 3)] = (m > 0.f) ? m / 127.f : 0.f;
    } else if (b < 12628) {
        qrow512(W1, W1q, ws1, (b - 12500) * 4 + (tid >> 6), tid & 63);
    } else if (b < 12756) {
        qrow512(W2, W2q, ws2, (b - 12628) * 4 + (tid >> 6), tid & 63);
    } else if (b < 12884) {
        cvt4(W3, W3b, (b - 12756) * 256 + tid);
    } else {
        int e = (b - 12884) * 256 + tid;
        if (e < E) atomicAdd(&deg[ei[E + e]], 1);
    }
}

// ---------------- hierarchical scan ----------------
__global__ void scanA_kernel(const int* __restrict__ deg, int* __restrict__ bsum, int n) {
    __shared__ int sm[256];
    int tid = threadIdx.x;
    int i = blockIdx.x * 256 + tid;
    sm[tid] = (i < n) ? deg[i] : 0;
    __syncthreads();
#pragma unroll
    for (int off = 128; off > 0; off >>= 1) {
        if (tid < off) sm[tid] += sm[tid + off];
        __syncthreads();
    }
    if (tid == 0) bsum[blockIdx.x] = sm[0];
}

__global__ void scanB_kernel(int* __restrict__ bsum, int nb) {
    __shared__ int sm[256];
    int tid = threadIdx.x;
    int v = (tid < nb) ? bsum[tid] : 0;
    sm[tid] = v;
    __syncthreads();
#pragma unroll
    for (int off = 1; off < 256; off <<= 1) {
        int t = (tid >= off) ? sm[tid - off] : 0;
        __syncthreads();
        sm[tid] += t;
        __syncthreads();
    }
    if (tid < nb) bsum[tid] = sm[tid] - v;
}

__global__ void scanC_kernel(const int* __restrict__ deg, const int* __restrict__ bsum,
                             int* __restrict__ rowp, int n) {
    __shared__ int sm[256];
    int tid = threadIdx.x;
    int b = blockIdx.x;
    int i = b * 256 + tid;
    int v = (i < n) ? deg[i] : 0;
    sm[tid] = v;
    __syncthreads();
#pragma unroll
    for (int off = 1; off < 256; off <<= 1) {
        int t = (tid >= off) ? sm[tid - off] : 0;
        __syncthreads();
        sm[tid] += t;
        __syncthreads();
    }
    if (i < n) rowp[i] = bsum[b] + sm[tid] - v;
    if (i == n - 1) rowp[n] = bsum[b] + sm[tid];
}

__global__ void fill_kernel(const int* __restrict__ ei, const int* __restrict__ rowp,
                            int* __restrict__ cnt, int* __restrict__ col, int E) {
    int e = blockIdx.x * blockDim.x + threadIdx.x;
    if (e < E) {
        int dst = ei[E + e];
        int pos = atomicAdd(&cnt[dst], 1);
        col[rowp[dst] + pos] = ei[e];
    }
}

// ---------------- int8 GIN aggregation (512 feats) -> int8 t + per-row scale ----------------
__global__ void agg_q512(const char* __restrict__ q, const float* __restrict__ sc,
                         char* __restrict__ tq, float* __restrict__ tsc,
                         const int* __restrict__ rowp, const int* __restrict__ col,
                         const float* __restrict__ epsp, int N) {
    int w = (blockIdx.x * blockDim.x + threadIdx.x) >> 6;
    if (w >= N) return;
    int lane = threadIdx.x & 63;
    float coef = 2.0f + epsp[0];
    const int2* base = (const int2*)q;
    int ch = lane >> 3;
    float acc[8];
#pragma unroll
    for (int j = 0; j < 8; j++) acc[j] = 0.f;
    float csum = 0.f;
    {
        float s = coef * sc[w * 8 + ch];
        csum += s;
        dq_accu(base[(size_t)w * 64 + lane], s, acc);
    }
    int p = rowp[w], e = rowp[w + 1];
    for (; p + 2 <= e; p += 2) {
        int s0 = __builtin_amdgcn_readfirstlane(col[p]);
        int s1 = __builtin_amdgcn_readfirstlane(col[p + 1]);
        int2 v0 = base[(size_t)s0 * 64 + lane];
        int2 v1 = base[(size_t)s1 * 64 + lane];
        float f0 = sc[s0 * 8 + ch];
        float f1 = sc[s1 * 8 + ch];
        csum += f0 + f1;
        dq_accu(v0, f0, acc);
        dq_accu(v1, f1, acc);
    }
    if (p < e) {
        int s0 = __builtin_amdgcn_readfirstlane(col[p]);
        float f0 = sc[s0 * 8 + ch];
        csum += f0;
        dq_accu(base[(size_t)s0 * 64 + lane], f0, acc);
    }
    // exact bias correction: acc held sum of s*(q+128); subtract 128*sum(s)
    float corr = 128.f * csum;
#pragma unroll
    for (int j = 0; j < 8; j++) acc[j] -= corr;
    // quantize t row to int8 with per-row scale (feeds i8 MFMA GEMM)
    float m = 0.f;
#pragma unroll
    for (int j = 0; j < 8; j++) m = fmaxf(m, fabsf(acc[j]));
#pragma unroll
    for (int d = 1; d < 64; d <<= 1) m = fmaxf(m, __shfl_xor(m, d));
    float qs = (m > 0.f) ? 127.f / m : 0.f;
    int lo = 0, hi = 0;
#pragma unroll
    for (int j = 0; j < 4; j++) { int qv = (int)rintf(acc[j] * qs); lo |= (qv & 0xFF) << (8 * j); }
#pragma unroll
    for (int j = 0; j < 4; j++) { int qv = (int)rintf(acc[j + 4] * qs); hi |= (qv & 0xFF) << (8 * j); }
    ((int2*)(tq + (size_t)w * 512))[lane] = make_int2(lo, hi);
    if (lane == 0) tsc[w] = (m > 0.f) ? m / 127.f : 0.f;
}

// ---------------- int8 layer-3 aggregation (256 feats, 4-chunk scales) -> fp32 ----------------
__global__ void agg3_q(const char* __restrict__ q, const float* __restrict__ sc,
                       float* __restrict__ out, const int* __restrict__ rowp,
                       const int* __restrict__ col, const float* __restrict__ epsp,
                       const float* __restrict__ bias, int N) {
    int w = (blockIdx.x * blockDim.x + threadIdx.x) >> 6;
    if (w >= N) return;
    int lane = threadIdx.x & 63;
    float coef = 2.0f + epsp[0];
    const int* base = (const int*)q;
    int ch = lane >> 4;
    f4v bv = *(const f4v*)(bias + lane * 4);
    float acc[4];
#pragma unroll
    for (int j = 0; j < 4; j++) acc[j] = 0.f;
    float csum = 0.f;
    {
        float s = coef * sc[w * 4 + ch];
        csum += s;
        dq_accu4(base[(size_t)w * 64 + lane], s, acc);
    }
    int p = rowp[w], e = rowp[w + 1];
    for (; p + 2 <= e; p += 2) {
        int s0 = __builtin_amdgcn_readfirstlane(col[p]);
        int s1 = __builtin_amdgcn_readfirstlane(col[p + 1]);
        int v0 = base[(size_t)s0 * 64 + lane];
        int v1 = base[(size_t)s1 * 64 + lane];
        float f0 = sc[s0 * 4 + ch];
        float f1 = sc[s1 * 4 + ch];
        csum += f0 + f1;
        dq_accu4(v0, f0, acc);
        dq_accu4(v1, f1, acc);
    }
    if (p < e) {
        int s0 = __builtin_amdgcn_readfirstlane(col[p]);
        float f0 = sc[s0 * 4 + ch];
        csum += f0;
        dq_accu4(base[(size_t)s0 * 64 + lane], f0, acc);
    }
    float corr = 128.f * csum;
    f4v o;
#pragma unroll
    for (int j = 0; j < 4; j++) {
        float v = acc[j] - corr + bv[j];
        o[j] = (v >= 0.f) ? v : 0.2f * v;
    }
    *(f4v*)(out + (size_t)w * 256 + lane * 4) = o;
}

// ---------------- int8 MFMA GEMM (i32 accum over full K, scale-once epilogue) ----------------
// MODE 1: bf16 out; MODE 2: int8 + per-(row,64col) scale out.
template <int MODE>
__launch_bounds__(256)
__global__ void gemm_i8_kernel(const char* __restrict__ A, const float* __restrict__ sA,
                               const char* __restrict__ Wq, const float* __restrict__ sW,
                               const float* __restrict__ bias, u16* __restrict__ C,
                               char* __restrict__ qc, float* __restrict__ scw,
                               int M, int Nout, int K, int nby) {
    int nwg = gridDim.x;
    int orig = blockIdx.x;
    int q8 = nwg >> 3, r8 = nwg & 7;
    int xcd = orig & 7, idx = orig >> 3;
    int wgid = (xcd < r8 ? xcd * (q8 + 1) : r8 * (q8 + 1) + (xcd - r8) * q8) + idx;
    int by = wgid % nby;
    int bx = wgid / nby;

    __shared__ alignas(16) char lA[2][128 * 64];
    __shared__ alignas(16) char lB[2][128 * 64];
    int tid = threadIdx.x;
    int lane = tid & 63;
    int wv = tid >> 6;
    int m0 = bx * 128;
    int n0 = by * 128;
    int wrow = (wv >> 1) * 64;
    int wcol = (wv & 1) * 64;

    i32x4 acc[4][4];
#pragma unroll
    for (int i = 0; i < 4; i++)
#pragma unroll
        for (int j = 0; j < 4; j++) acc[i][j] = (i32x4){0, 0, 0, 0};

    int srow = lane >> 2;
    int scol = (lane & 3) * 16;
    int arow0 = m0 + wv * 16 + srow;        if (arow0 >= M) arow0 = M - 1;
    int arow1 = m0 + 64 + wv * 16 + srow;   if (arow1 >= M) arow1 = M - 1;
    const char* gA0 = A + (size_t)arow0 * K + scol;
    const char* gA1 = A + (size_t)arow1 * K + scol;
    const char* gB0 = Wq + (size_t)(n0 + wv * 16 + srow) * K + scol;
    const char* gB1 = Wq + (size_t)(n0 + 64 + wv * 16 + srow) * K + scol;
    int la0 = (wv * 16) * 64;
    int la1 = (64 + wv * 16) * 64;

    int fr = lane & 15;
    int kq = (lane >> 4) * 16;
    int nt = K / 64;

    gload16(gA0, lA[0] + la0);
    gload16(gA1, lA[0] + la1);
    gload16(gB0, lB[0] + la0);
    gload16(gB1, lB[0] + la1);
    __syncthreads();

    for (int t = 0; t < nt; t++) {
        int cur = t & 1;
        if (t + 1 < nt) {
            int kt = (t + 1) * 64;
            gload16(gA0 + kt, lA[cur ^ 1] + la0);
            gload16(gA1 + kt, lA[cur ^ 1] + la1);
            gload16(gB0 + kt, lB[cur ^ 1] + la0);
            gload16(gB1 + kt, lB[cur ^ 1] + la1);
        }
        i32x4 af[4], bf[4];
#pragma unroll
        for (int m = 0; m < 4; m++)
            af[m] = *(const i32x4*)(lA[cur] + (wrow + m * 16 + fr) * 64 + kq);
#pragma unroll
        for (int nf = 0; nf < 4; nf++)
            bf[nf] = *(const i32x4*)(lB[cur] + (wcol + nf * 16 + fr) * 64 + kq);
#pragma unroll
        for (int m = 0; m < 4; m++)
#pragma unroll
            for (int nf = 0; nf < 4; nf++)
                acc[m][nf] = __builtin_amdgcn_mfma_i32_16x16x64_i8(af[m], bf[nf], acc[m][nf], 0, 0, 0);
        __syncthreads();
    }

    int r0 = (lane >> 4) * 4;
#pragma unroll
    for (int m = 0; m < 4; m++) {
        float sa[4];
#pragma unroll
        for (int r = 0; r < 4; r++) {
            int gr = m0 + wrow + m * 16 + r0 + r;
            sa[r] = sA[gr < M ? gr : M - 1];
        }
        float v[4][4];
#pragma unroll
        for (int nf = 0; nf < 4; nf++) {
            int gc = n0 + wcol + nf * 16 + fr;
            float swv = sW[gc];
            float bv = bias[gc];
#pragma unroll
            for (int r = 0; r < 4; r++) {
                float tv = (float)acc[m][nf][r] * sa[r] * swv + bv;
                v[nf][r] = (tv >= 0.f) ? tv : 0.2f * tv;
            }
        }
        if constexpr (MODE == 1) {
#pragma unroll
            for (int nf = 0; nf < 4; nf++) {
                int gc = n0 + wcol + nf * 16 + fr;
#pragma unroll
                for (int r = 0; r < 4; r++) {
                    int gr = m0 + wrow + m * 16 + r0 + r;
                    if (gr < M) C[(size_t)gr * Nout + gc] = f2b(v[nf][r]);
                }
            }
        } else {
            int nch = Nout >> 6;
            int chunk = (n0 + wcol) >> 6;
#pragma unroll
            for (int r = 0; r < 4; r++) {
                float amax = fmaxf(fmaxf(fabsf(v[0][r]), fabsf(v[1][r])),
                                   fmaxf(fabsf(v[2][r]), fabsf(v[3][r])));
#pragma unroll
                for (int d = 1; d < 16; d <<= 1) amax = fmaxf(amax, __shfl_xor(amax, d));
                int gr = m0 + wrow + m * 16 + r0 + r;
                float scale = (amax > 0.f) ? 127.f / amax : 0.f;
                if (gr < M) {
#pragma unroll
                    for (int nf = 0; nf < 4; nf++) {
                        int qv = (int)rintf(v[nf][r] * scale);
                        qc[(size_t)gr * Nout + n0 + wcol + nf * 16 + fr] = (signed char)qv;
                    }
                    if (fr == 0)
                        scw[(size_t)gr * nch + chunk] = (amax > 0.f) ? amax / 127.f : 0.f;
                }
            }
        }
    }
}

// ---------------- bf16 MFMA GEMM (layer 3 only): 2-phase dbuf, fused int8-quant out ----------------
#define BM 128
#define BN 128
#define BK 32

__launch_bounds__(256)
__global__ void gemm_bt_kernel(const u16* __restrict__ A, const u16* __restrict__ W,
                               char* __restrict__ qc, float* __restrict__ scw,
                               int M, int Nout, int K, int nby) {
    int nwg = gridDim.x;
    int orig = blockIdx.x;
    int q8 = nwg >> 3, r8 = nwg & 7;
    int xcd = orig & 7, idx = orig >> 3;
    int wgid = (xcd < r8 ? xcd * (q8 + 1) : r8 * (q8 + 1) + (xcd - r8) * q8) + idx;
    int by = wgid % nby;
    int bx = wgid / nby;

    __shared__ alignas(16) u16 lA[2][BM * BK];
    __shared__ alignas(16) u16 lB[2][BN * BK];
    int tid = threadIdx.x;
    int lane = tid & 63;
    int wv = tid >> 6;
    int m0 = bx * BM;
    int n0 = by * BN;
    int wrow = (wv >> 1) * 64;
    int wcol = (wv & 1) * 64;

    f32x4 acc[4][4];
#pragma unroll
    for (int i = 0; i < 4; i++)
#pragma unroll
        for (int j = 0; j < 4; j++) acc[i][j] = (f32x4){0.f, 0.f, 0.f, 0.f};

    int srow = lane >> 2;
    int scol = (lane & 3) * 8;
    int arow0 = m0 + wv * 16 + srow;        if (arow0 >= M) arow0 = M - 1;
    int arow1 = m0 + 64 + wv * 16 + srow;   if (arow1 >= M) arow1 = M - 1;
    const u16* gA0 = A + (size_t)arow0 * K + scol;
    const u16* gA1 = A + (size_t)arow1 * K + scol;
    const u16* gB0 = W + (size_t)(n0 + wv * 16 + srow) * K + scol;
    const u16* gB1 = W + (size_t)(n0 + 64 + wv * 16 + srow) * K + scol;
    int la0 = (wv * 16) * BK;
    int la1 = (64 + wv * 16) * BK;

    int fr = lane & 15;
    int kq = (lane >> 4) * 8;
    int nt = K / BK;

    gload16(gA0, lA[0] + la0);
    gload16(gA1, lA[0] + la1);
    gload16(gB0, lB[0] + la0);
    gload16(gB1, lB[0] + la1);
    __syncthreads();

    for (int t = 0; t < nt; t++) {
        int cur = t & 1;
        if (t + 1 < nt) {
            int kt = (t + 1) * BK;
            gload16(gA0 + kt, lA[cur ^ 1] + la0);
            gload16(gA1 + kt, lA[cur ^ 1] + la1);
            gload16(gB0 + kt, lB[cur ^ 1] + la0);
            gload16(gB1 + kt, lB[cur ^ 1] + la1);
        }
        bf16x8 af[4], bfr[4];
#pragma unroll
        for (int m = 0; m < 4; m++)
            af[m] = *(const bf16x8*)(lA[cur] + (wrow + m * 16 + fr) * BK + kq);
#pragma unroll
        for (int nf = 0; nf < 4; nf++)
            bfr[nf] = *(const bf16x8*)(lB[cur] + (wcol + nf * 16 + fr) * BK + kq);
#pragma unroll
        for (int m = 0; m < 4; m++)
#pragma unroll
            for (int nf = 0; nf < 4; nf++)
                acc[m][nf] = __builtin_amdgcn_mfma_f32_16x16x32_bf16(af[m], bfr[nf], acc[m][nf], 0, 0, 0);
        __syncthreads();
    }

    // fused int8-quant epilogue (no bias/act — layer-3 commuted GEMM)
    int r0 = (lane >> 4) * 4;
    int nch = Nout >> 6;
    int chunk = (n0 + wcol) >> 6;
#pragma unroll
    for (int m = 0; m < 4; m++) {
        float v[4][4];
#pragma unroll
        for (int nf = 0; nf < 4; nf++)
#pragma unroll
            for (int r = 0; r < 4; r++) v[nf][r] = acc[m][nf][r];
#pragma unroll
        for (int r = 0; r < 4; r++) {
            float amax = fmaxf(fmaxf(fabsf(v[0][r]), fabsf(v[1][r])),
                               fmaxf(fabsf(v[2][r]), fabsf(v[3][r])));
#pragma unroll
            for (int d = 1; d < 16; d <<= 1) amax = fmaxf(amax, __shfl_xor(amax, d));
            int gr = m0 + wrow + m * 16 + r0 + r;
            float scale = (amax > 0.f) ? 127.f / amax : 0.f;
            if (gr < M) {
#pragma unroll
                for (int nf = 0; nf < 4; nf++) {
                    int qv = (int)rintf(v[nf][r] * scale);
                    qc[(size_t)gr * Nout + n0 + wcol + nf * 16 + fr] = (signed char)qv;
                }
                if (fr == 0)
                    scw[(size_t)gr * nch + chunk] = (amax > 0.f) ? amax / 127.f : 0.f;
            }
        }
    }
}

// ---------------- final fc: 8 central nodes per block (shared W stream) ----------------
__global__ void fc_kernel(const float* __restrict__ x3, const int* __restrict__ cidx,
                          const float* __restrict__ W, const float* __restrict__ b,
                          float* __restrict__ out, int C, int F, int Kc) {
    __shared__ float xr[8][256];
    int base = blockIdx.x * 8;
    int tid = threadIdx.x;
#pragma unroll
    for (int j = 0; j < 8; j++) {
        int k = base + j;
        if (k < Kc) xr[j][tid] = x3[(size_t)cidx[k] * C + tid];
    }
    __syncthreads();
    for (int f = tid; f < F; f += 256) {
        const float4* wr = (const float4*)(W + (size_t)f * C);
        float acc[8];
#pragma unroll
        for (int j = 0; j < 8; j++) acc[j] = 0.f;
        for (int c4 = 0; c4 < C / 4; ++c4) {
            float4 wv = wr[c4];
#pragma unroll
            for (int j = 0; j < 8; j++) {
                acc[j] += xr[j][c4 * 4 + 0] * wv.x + xr[j][c4 * 4 + 1] * wv.y +
                          xr[j][c4 * 4 + 2] * wv.z + xr[j][c4 * 4 + 3] * wv.w;
            }
        }
        float bf = b[f];
#pragma unroll
        for (int j = 0; j < 8; j++) {
            int k = base + j;
            if (k < Kc) out[(size_t)k * F + f] = acc[j] + bf;
        }
    }
}

extern "C" void kernel_launch(void* const* d_in, const int* in_sizes, int n_in,
                              void* d_out, int out_size, void* d_ws, size_t ws_size,
                              hipStream_t stream) {
    const float* x    = (const float*)d_in[0];
    const int*   ei   = (const int*)d_in[1];
    const int*   cidx = (const int*)d_in[2];
    const float* W1   = (const float*)d_in[3];
    const float* b1   = (const float*)d_in[4];
    const float* eps1 = (const float*)d_in[5];
    const float* W2   = (const float*)d_in[6];
    const float* b2   = (const float*)d_in[7];
    const float* eps2 = (const float*)d_in[8];
    const float* W3   = (const float*)d_in[9];
    const float* b3   = (const float*)d_in[10];
    const float* eps3 = (const float*)d_in[11];
    const float* Wfc  = (const float*)d_in[12];
    const float* bfc  = (const float*)d_in[13];

    const int F = 512, H = 512, Cc = 256;
    const int Nn = in_sizes[0] / F;   // 50000
    const int E  = in_sizes[1] / 2;   // 800000
    const int Kc = in_sizes[2];       // 1024

    // workspace layout
    const size_t SZ_Q = (size_t)Nn * 512;  // 25.6 MB int8 plane
    char* ws = (char*)d_ws;
    char*  tq   = ws;                              // int8 t (agg output)
    char*  qbuf = ws + SZ_Q;                       // int8 h / g (gather source)
    float* tsc  = (float*)(ws + 2 * SZ_Q);         // per-row t scales
    float* sc   = tsc + Nn;                        // per-(row,64chunk) gather scales (Nn*8)
    char*  W1q  = (char*)(sc + (size_t)Nn * 8);
    float* ws1  = (float*)(W1q + 262144);
    char*  W2q  = (char*)(ws1 + 512);
    float* ws2  = (float*)(W2q + 262144);
    u16*   W3b  = (u16*)(ws2 + 512);
    int*   deg  = (int*)((char*)W3b + 262144);
    int*   cnt  = deg + Nn;
    int*   rowp = cnt + Nn;
    int*   colx = rowp + Nn + 1;
    int*   bsum = colx + E;

    // h2 (bf16) lives in d_out's x3 region; overwritten by agg3 at the end
    u16* hbuf = (u16*)d_out;

    int nbScan = (Nn + 255) / 256;

    hipMemsetAsync(deg, 0, 2 * (size_t)Nn * sizeof(int), stream);
    int prepBlocks = 12884 + (E + 255) / 256;
    prep_kernel<<<prepBlocks, 256, 0, stream>>>(x, qbuf, sc, W1, W1q, ws1, W2, W2q, ws2,
                                                W3, W3b, ei, deg, E);
    scanA_kernel<<<nbScan, 256, 0, stream>>>(deg, bsum, Nn);
    scanB_kernel<<<1, 256, 0, stream>>>(bsum, nbScan);
    scanC_kernel<<<nbScan, 256, 0, stream>>>(deg, bsum, rowp, Nn);
    fill_kernel<<<(E + 255) / 256, 256, 0, stream>>>(ei, rowp, cnt, colx, E);

    int aggBlocks = (Nn * 64 + 255) / 256;
    int nbx = (Nn + 127) / 128;  // 391

    // layer 1: agg(qx) -> int8 t1; i8-GEMM -> int8 h1 (fused quant, 8 chunk scales)
    agg_q512<<<aggBlocks, 256, 0, stream>>>(qbuf, sc, tq, tsc, rowp, colx, eps1, Nn);
    gemm_i8_kernel<2><<<nbx * 4, 256, 0, stream>>>(tq, tsc, W1q, ws1, b1, nullptr,
                                                   qbuf, sc, Nn, H, F, 4);
    // layer 2: agg(qh1) -> int8 t2; i8-GEMM -> bf16 h2
    agg_q512<<<aggBlocks, 256, 0, stream>>>(qbuf, sc, tq, tsc, rowp, colx, eps2, Nn);
    gemm_i8_kernel<1><<<nbx * 4, 256, 0, stream>>>(tq, tsc, W2q, ws2, b2, hbuf,
                                                   nullptr, nullptr, Nn, H, H, 4);
    // layer 3 commuted: g = h2 @ W3^T (bf16 MFMA) -> int8 qg; then aggregate
    gemm_bt_kernel<<<nbx * 2, 256, 0, stream>>>(hbuf, W3b, qbuf, sc, Nn, Cc, H, 2);
    float* x3 = (float*)d_out;
    agg3_q<<<aggBlocks, 256, 0, stream>>>(qbuf, sc, x3, rowp, colx, eps3, b3, Nn);

    // fc
    float* outp = x3 + (size_t)Nn * Cc;
    fc_kernel<<<(Kc + 7) / 8, 256, 0, stream>>>(x3, cidx, Wfc, bfc, outp, Cc, F, Kc);
}